// Round 6
// baseline (4722.837 us; speedup 1.0000x reference)
//
#include <hip/hip_runtime.h>
#include <math.h>

typedef __bf16 bf16;
typedef __bf16 bf16x8 __attribute__((ext_vector_type(8)));
typedef __bf16 bf16x4 __attribute__((ext_vector_type(4)));
typedef float  floatx4 __attribute__((ext_vector_type(4)));

// dims
#define BB 1024
#define TT 120
#define FF 32
#define DD 128
#define NROWS (BB*TT)      // 122880
#define HOR 90
#define MM 5

// ---------------------------------------------------------------------------
// Encoder weights -> split bf16 pair (hi = bf16(w), lo = bf16(w - hi)).
__global__ __launch_bounds__(256) void prep_weights(
    const float* __restrict__ qkv, const float* __restrict__ outw,
    const float* __restrict__ f1,  const float* __restrict__ f2,
    bf16* __restrict__ dhi, bf16* __restrict__ dlo)
{
    int i = blockIdx.x*256 + threadIdx.x;
    if (i >= 393216) return;
    float v;
    if      (i < 98304)  v = qkv[i];
    else if (i < 131072) v = outw[i - 98304];
    else if (i < 262144) v = f1[i - 131072];
    else                 v = f2[i - 262144];
    bf16 h = (bf16)v;
    dhi[i] = h;
    dlo[i] = (bf16)(v - (float)h);
}

// ---------------------------------------------------------------------------
// FRESH input projection rewrite: one block (128 thr) per row, serial dot,
// direct global weight reads, per-column PE from even base index.
__global__ __launch_bounds__(128) void inproj2(
    const float* __restrict__ x, const int* __restrict__ sym_id,
    const float* __restrict__ sym_emb, const float* __restrict__ in_w,
    const float* __restrict__ in_b, float* __restrict__ h)
{
    __shared__ float xin[48];
    const int row = blockIdx.x;          // 0..NROWS-1
    const int d   = threadIdx.x;         // 0..127
    const int b   = row / TT;
    const int t   = row % TT;
    if (d < 32)      xin[d] = x[(size_t)row*FF + d];
    else if (d < 48) xin[d] = sym_emb[(size_t)sym_id[b]*16 + (d - 32)];
    __syncthreads();
    float a = in_b[d];
    const float* wr = in_w + (size_t)d*48;
    for (int k = 0; k < 48; ++k) a += xin[k] * wr[k];
    // sinusoidal PE: column d, frequency from even base di = d & ~1
    const int di = d & ~1;
    const float f = expf((float)di * (-9.210340371976184f / 128.f));
    const float arg = (float)t * f;
    a += (d & 1) ? cosf(arg) : sinf(arg);
    h[(size_t)row*DD + d] = a;
}

// ---------------------------------------------------------------------------
// FRESH LayerNorm rewrite: one block (128 thr) per row, LDS tree reduction,
// two-pass variance. fp32 -> fp32.
__global__ __launch_bounds__(128) void ln2(
    const float* __restrict__ h, const float* __restrict__ w,
    const float* __restrict__ b, float* __restrict__ y)
{
    __shared__ float red[128];
    __shared__ float mean_s, rstd_s;
    const int row = blockIdx.x;
    const int d = threadIdx.x;
    const float v = h[(size_t)row*DD + d];
    red[d] = v;
    __syncthreads();
    for (int s = 64; s > 0; s >>= 1) {
        if (d < s) red[d] += red[d + s];
        __syncthreads();
    }
    if (d == 0) mean_s = red[0] * (1.f/128.f);
    __syncthreads();
    const float m = mean_s;
    const float dv = v - m;
    red[d] = dv * dv;
    __syncthreads();
    for (int s = 64; s > 0; s >>= 1) {
        if (d < s) red[d] += red[d + s];
        __syncthreads();
    }
    if (d == 0) rstd_s = rsqrtf(red[0] * (1.f/128.f) + 1e-5f);
    __syncthreads();
    y[(size_t)row*DD + d] = dv * rstd_s * w[d] + b[d];
}

// ---------------------------------------------------------------------------
// Split-precision MFMA GEMM (unchanged; exonerated by R2/R4 A-B).
template<int EPI>
__global__ __launch_bounds__(256) void gemm_split(
    const float* __restrict__ A, const bf16* __restrict__ Whi,
    const bf16* __restrict__ Wlo, const float* __restrict__ bias,
    const float* __restrict__ res, float* __restrict__ outp, int N, int K)
{
    __shared__ alignas(16) bf16 smem[4*128*64];
    bf16* Ah = smem;
    bf16* Al = smem + 8192;
    bf16* Wh = smem + 16384;
    bf16* Wl = smem + 24576;
    const int tid = threadIdx.x;
    const int lane = tid & 63, wave = tid >> 6;
    const int q = lane >> 4, ml = lane & 15;
    const int wm = (wave & 1) * 64, wn = (wave >> 1) * 64;
    const int m0 = blockIdx.x * 128, n0 = blockIdx.y * 128;
    floatx4 acc[4][4];
    #pragma unroll
    for (int i = 0; i < 4; ++i)
        #pragma unroll
        for (int j = 0; j < 4; ++j) acc[i][j] = (floatx4){0.f,0.f,0.f,0.f};
    const int nkb = K >> 6;
    for (int kb = 0; kb < nkb; ++kb) {
        #pragma unroll
        for (int i = 0; i < 4; ++i) {
            int idx = i*256 + tid;
            int r = idx >> 3, c = idx & 7;
            int sw = ((c ^ (r & 7)) * 8);
            {
                const float* ap = A + (size_t)(m0 + r)*K + kb*64 + c*8;
                float4 f0 = *(const float4*)ap;
                float4 f1 = *(const float4*)(ap + 4);
                float v[8] = {f0.x,f0.y,f0.z,f0.w,f1.x,f1.y,f1.z,f1.w};
                bf16x8 hi, lo;
                #pragma unroll
                for (int j = 0; j < 8; ++j) {
                    bf16 hb = (bf16)v[j];
                    hi[j] = hb;
                    lo[j] = (bf16)(v[j] - (float)hb);
                }
                *(bf16x8*)&Ah[r*64 + sw] = hi;
                *(bf16x8*)&Al[r*64 + sw] = lo;
            }
            {
                size_t wo = (size_t)(n0 + r)*K + kb*64 + c*8;
                *(uint4*)&Wh[r*64 + sw] = *(const uint4*)(Whi + wo);
                *(uint4*)&Wl[r*64 + sw] = *(const uint4*)(Wlo + wo);
            }
        }
        __syncthreads();
        #pragma unroll
        for (int s = 0; s < 2; ++s) {
            bf16x8 ah[4], al[4], bh[4], bl[4];
            #pragma unroll
            for (int t = 0; t < 4; ++t) {
                int ra = wm + t*16 + ml;
                int oa = ra*64 + (((s*4+q) ^ (ra & 7))*8);
                ah[t] = *(const bf16x8*)&Ah[oa];
                al[t] = *(const bf16x8*)&Al[oa];
                int rb = wn + t*16 + ml;
                int ob = rb*64 + (((s*4+q) ^ (rb & 7))*8);
                bh[t] = *(const bf16x8*)&Wh[ob];
                bl[t] = *(const bf16x8*)&Wl[ob];
            }
            #pragma unroll
            for (int i = 0; i < 4; ++i)
                #pragma unroll
                for (int j = 0; j < 4; ++j) {
                    acc[i][j] = __builtin_amdgcn_mfma_f32_16x16x32_bf16(ah[i], bh[j], acc[i][j], 0, 0, 0);
                    acc[i][j] = __builtin_amdgcn_mfma_f32_16x16x32_bf16(ah[i], bl[j], acc[i][j], 0, 0, 0);
                    acc[i][j] = __builtin_amdgcn_mfma_f32_16x16x32_bf16(al[i], bh[j], acc[i][j], 0, 0, 0);
                }
        }
        __syncthreads();
    }
    #pragma unroll
    for (int j = 0; j < 4; ++j) {
        int col = n0 + wn + j*16 + ml;
        float bv = bias[col];
        #pragma unroll
        for (int i = 0; i < 4; ++i) {
            #pragma unroll
            for (int r = 0; r < 4; ++r) {
                int row = m0 + wm + i*16 + q*4 + r;
                size_t o = (size_t)row * N + col;
                float v = acc[i][j][r] + bv;
                if      (EPI == 1) v = fmaxf(v, 0.f);
                else if (EPI == 2) v += res[o];
                outp[o] = v;
            }
        }
    }
}

// ---------------------------------------------------------------------------
// Naive fp32 attention (unchanged from R5). One block per (b,h).
__global__ __launch_bounds__(256) void attn_naive(
    const float* __restrict__ qkv, float* __restrict__ O)
{
    __shared__ float Qs[120*33];
    __shared__ float Ks[120*33];
    __shared__ float Vs[120*33];
    __shared__ float Sp[4][128];
    const int tid = threadIdx.x, lane = tid & 63, wave = tid >> 6;
    const int b = blockIdx.x >> 2, hh = blockIdx.x & 3;
    const float* base = qkv + (size_t)b*TT*384 + hh*32;
    for (int i = tid; i < 120*32; i += 256) {
        int t = i >> 5, d = i & 31;
        Qs[t*33 + d] = base[(size_t)t*384 + d];
        Ks[t*33 + d] = base[(size_t)t*384 + 128 + d];
        Vs[t*33 + d] = base[(size_t)t*384 + 256 + d];
    }
    __syncthreads();
    const float scale = 0.17677669529663687f;   // 1/sqrt(32)
    for (int ti = 0; ti < 30; ++ti) {
        const int t = wave*30 + ti;
        const int u1 = lane + 64;
        float s0 = 0.f, s1 = 0.f;
        for (int d = 0; d < 32; ++d) {
            float qd = Qs[t*33 + d];
            s0 += qd * Ks[lane*33 + d];
            if (u1 < TT) s1 += qd * Ks[u1*33 + d];
        }
        s0 *= scale;
        s1 = (u1 < TT) ? s1*scale : -3e38f;
        float mx = fmaxf(s0, s1);
        #pragma unroll
        for (int o = 1; o < 64; o <<= 1) mx = fmaxf(mx, __shfl_xor(mx, o));
        float e0 = expf(s0 - mx);
        float e1 = (u1 < TT) ? expf(s1 - mx) : 0.f;
        float sm = e0 + e1;
        #pragma unroll
        for (int o = 1; o < 64; o <<= 1) sm += __shfl_xor(sm, o);
        float inv = 1.f/sm;
        Sp[wave][lane]      = e0*inv;
        Sp[wave][lane + 64] = e1*inv;
        __syncthreads();
        if (lane < 32) {
            float oa = 0.f;
            for (int u = 0; u < TT; ++u) oa += Sp[wave][u] * Vs[u*33 + lane];
            O[((size_t)b*TT + t)*DD + hh*32 + lane] = oa;
        }
        __syncthreads();
    }
}

// ---------------------------------------------------------------------------
// Pool+ctx+rv (unchanged from R5).
__global__ __launch_bounds__(128) void pool_ctx2(
    const float* __restrict__ h, const float* __restrict__ x,
    const int* __restrict__ sym_id, const int* __restrict__ regime_id,
    const float* __restrict__ sym_emb, const float* __restrict__ reg_emb,
    const float* __restrict__ pool_w, const float* __restrict__ pool_b,
    const float* __restrict__ ctx_w, const float* __restrict__ ctx_b,
    float* __restrict__ ctxf, float* __restrict__ rv)
{
    __shared__ float aw[120];
    __shared__ float cat[152];
    const int b = blockIdx.x;
    const int tid = threadIdx.x;
    const float* hb = h + (size_t)b*TT*DD;
    if (tid < 120) {
        float s = pool_b[0];
        for (int k = 0; k < 128; ++k) s += hb[(size_t)tid*DD + k] * pool_w[k];
        aw[tid] = s;
    }
    __syncthreads();
    if (tid == 0) {
        float mx = -3e38f;
        for (int t = 0; t < TT; ++t) mx = fmaxf(mx, aw[t]);
        float sm = 0.f;
        for (int t = 0; t < TT; ++t) { float e = expf(aw[t]-mx); aw[t] = e; sm += e; }
        float inv = 1.f/sm;
        for (int t = 0; t < TT; ++t) aw[t] *= inv;
    } else if (tid == 64) {
        float s = 0.f;
        for (int t = 0; t < TT; ++t) s += x[((size_t)b*TT + t)*FF];
        float mean = s / 120.f;
        float ss = 0.f;
        for (int t = 0; t < TT; ++t) {
            float d0 = x[((size_t)b*TT + t)*FF] - mean;
            ss += d0*d0;
        }
        rv[b] = sqrtf(ss / 119.f);
    }
    __syncthreads();
    {
        float p = 0.f;
        for (int t = 0; t < TT; ++t) p += aw[t] * hb[(size_t)t*DD + tid];
        cat[tid] = p;
    }
    if (tid < 16)      cat[128 + tid] = sym_emb[(size_t)sym_id[b]*16 + tid];
    else if (tid < 24) cat[144 + (tid-16)] = reg_emb[regime_id[b]*8 + (tid-16)];
    __syncthreads();
    float acc = ctx_b[tid];
    const float* wr = ctx_w + (size_t)tid*152;
    for (int j = 0; j < 152; ++j) acc += cat[j] * wr[j];
    ctxf[(size_t)b*128 + tid] = acc;
}

// ---------------------------------------------------------------------------
// GRU (unchanged from R5). One thread per (row,dim).
__global__ __launch_bounds__(256) void gru2_kernel(
    const float* __restrict__ ctxf, const float* __restrict__ wih,
    const float* __restrict__ bih, const float* __restrict__ whh,
    const float* __restrict__ bhh,
    const float* __restrict__ mu_w1, const float* __restrict__ mu_b1,
    const float* __restrict__ mu_w2, const float* __restrict__ mu_b2,
    const float* __restrict__ vol_w1, const float* __restrict__ vol_b1,
    const float* __restrict__ vol_w2, const float* __restrict__ vol_b2,
    const float* __restrict__ rv, float* __restrict__ out)
{
    __shared__ float hd[2][128];
    __shared__ float gictx[2][384];
    __shared__ float g1[2][128];
    __shared__ float stp[2][5];
    __shared__ float mu_s[2][5], sg_s[2][5];
    const int tid = threadIdx.x;
    const int rr = tid >> 7, d = tid & 127;
    const int b = blockIdx.x*2 + rr;
    float c = ctxf[(size_t)b*128 + d];
    hd[rr][d] = c;
    if (d < 5) stp[rr][d] = 0.f;
    __syncthreads();
    #pragma unroll
    for (int g = 0; g < 3; ++g) {
        int n = g*128 + d;
        const float* wr = wih + (size_t)n*133 + 5;
        float a = bih[n];
        for (int k = 0; k < 128; ++k) a += hd[rr][k] * wr[k];
        gictx[rr][n] = a;
    }
    __syncthreads();
    const float rvb = 1.f + rv[b];
    for (int st = 0; st < HOR; ++st) {
        float hr = bhh[d], hz = bhh[128+d], hn = bhh[256+d];
        const float* w_r = whh + (size_t)d*128;
        const float* w_z = whh + (size_t)(128+d)*128;
        const float* w_n = whh + (size_t)(256+d)*128;
        for (int k = 0; k < 128; ++k) {
            float hv = hd[rr][k];
            hr += hv * w_r[k];
            hz += hv * w_z[k];
            hn += hv * w_n[k];
        }
        float ir = gictx[rr][d], iz = gictx[rr][128+d], in_ = gictx[rr][256+d];
        #pragma unroll
        for (int j = 0; j < 5; ++j) {
            float sv = stp[rr][j];
            ir  += sv * wih[(size_t)d*133 + j];
            iz  += sv * wih[(size_t)(128+d)*133 + j];
            in_ += sv * wih[(size_t)(256+d)*133 + j];
        }
        float rg = 1.f/(1.f + expf(-(ir + hr)));
        float zg = 1.f/(1.f + expf(-(iz + hz)));
        float nn = tanhf(in_ + rg*hn);
        float hnew = (1.f - zg)*nn + zg*hd[rr][d];
        __syncthreads();
        hd[rr][d] = hnew;
        __syncthreads();
        {
            const float* w1 = (d < 64) ? (mu_w1 + (size_t)d*128)
                                       : (vol_w1 + (size_t)(d-64)*128);
            float a = (d < 64) ? mu_b1[d] : vol_b1[d-64];
            for (int k = 0; k < 128; ++k) a += hd[rr][k] * w1[k];
            g1[rr][d] = 0.5f*a*(1.f + erff(a*0.70710678118654752f));
        }
        __syncthreads();
        if (d < 10) {
            if (d < 5) {
                float a = mu_b2[d];
                const float* w2 = mu_w2 + d*64;
                for (int j = 0; j < 64; ++j) a += g1[rr][j]*w2[j];
                mu_s[rr][d] = tanhf(a);
            } else {
                int oo = d - 5;
                float a = vol_b2[oo];
                const float* w2 = vol_w2 + oo*64;
                for (int j = 0; j < 64; ++j) a += g1[rr][64+j]*w2[j];
                float sp = (a > 20.f) ? a : log1pf(expf(a));
                sg_s[rr][oo] = sp * rvb;
            }
        }
        __syncthreads();
        if (d < 5) {
            float pr = mu_s[rr][d] * sg_s[rr][d];
            stp[rr][d] = pr;
            out[((size_t)b*HOR + st)*MM + d] = pr;
        }
        __syncthreads();
    }
}

// ---------------------------------------------------------------------------
extern "C" void kernel_launch(void* const* d_in, const int* in_sizes, int n_in,
                              void* d_out, int out_size, void* d_ws, size_t ws_size,
                              hipStream_t stream)
{
    (void)in_sizes; (void)n_in; (void)out_size;
    const float* x        = (const float*)d_in[0];
    const int*   sym_id   = (const int*)d_in[1];
    const int*   regime_id= (const int*)d_in[2];
    const float* sym_emb  = (const float*)d_in[3];
    const float* reg_emb  = (const float*)d_in[4];
    const float* in_w     = (const float*)d_in[5];
    const float* in_b     = (const float*)d_in[6];
    const float* qkv_w    = (const float*)d_in[7];
    const float* qkv_b    = (const float*)d_in[8];
    const float* out_w    = (const float*)d_in[9];
    const float* out_bv   = (const float*)d_in[10];
    const float* ln1_w    = (const float*)d_in[11];
    const float* ln1_b    = (const float*)d_in[12];
    const float* ln2_w    = (const float*)d_in[13];
    const float* ln2_b    = (const float*)d_in[14];
    const float* f1_w     = (const float*)d_in[15];
    const float* f1_b     = (const float*)d_in[16];
    const float* f2_w     = (const float*)d_in[17];
    const float* f2_b     = (const float*)d_in[18];
    const float* pool_w   = (const float*)d_in[19];
    const float* pool_b   = (const float*)d_in[20];
    const float* ctx_w    = (const float*)d_in[21];
    const float* ctx_b    = (const float*)d_in[22];
    const float* gru_wih  = (const float*)d_in[23];
    const float* gru_whh  = (const float*)d_in[24];
    const float* gru_bih  = (const float*)d_in[25];
    const float* gru_bhh  = (const float*)d_in[26];
    const float* mu_w1    = (const float*)d_in[27];
    const float* mu_b1    = (const float*)d_in[28];
    const float* mu_w2    = (const float*)d_in[29];
    const float* mu_b2    = (const float*)d_in[30];
    const float* vol_w1   = (const float*)d_in[31];
    const float* vol_b1   = (const float*)d_in[32];
    const float* vol_w2   = (const float*)d_in[33];
    const float* vol_b2   = (const float*)d_in[34];
    float* outp = (float*)d_out;

    char* ws = (char*)d_ws;
    size_t off = 0;
    auto alloc = [&](size_t bytes) -> void* {
        void* p = ws + off;
        off = (off + bytes + 255) & ~(size_t)255;
        return p;
    };
    float* h    = (float*)alloc((size_t)NROWS*DD*4);        // 62.9 MB
    float* y    = (float*)alloc((size_t)NROWS*DD*4);        // 62.9 MB
    bf16*  whi  = (bf16*) alloc((size_t)393216*2);
    bf16*  wlo  = (bf16*) alloc((size_t)393216*2);
    float* ctxf = (float*)alloc((size_t)BB*DD*4);
    float* rv   = (float*)alloc((size_t)BB*4);
    size_t avail = (ws_size > off) ? (ws_size - off) : 0;
    int nch;
    if      (avail >= (size_t)NROWS*512*4)     nch = 1;
    else if (avail >= (size_t)NROWS/2*512*4)   nch = 2;
    else                                       nch = 4;
    const int RC = NROWS / nch;
    const int BC = BB / nch;
    float* big = (float*)(ws + off);

    prep_weights<<<1536, 256, 0, stream>>>(qkv_w, out_w, f1_w, f2_w, whi, wlo);
    inproj2<<<NROWS, 128, 0, stream>>>(x, sym_id, sym_emb, in_w, in_b, h);

    for (int l = 0; l < 2; ++l) {
        const bf16* wqkv_h = whi + l*49152;          const bf16* wqkv_l = wlo + l*49152;
        const bf16* wout_h = whi + 98304 + l*16384;  const bf16* wout_l = wlo + 98304 + l*16384;
        const bf16* wf1_h  = whi + 131072 + l*65536; const bf16* wf1_l  = wlo + 131072 + l*65536;
        const bf16* wf2_h  = whi + 262144 + l*65536; const bf16* wf2_l  = wlo + 262144 + l*65536;
        ln2<<<NROWS, 128, 0, stream>>>(h, ln1_w + l*128, ln1_b + l*128, y);
        for (int c = 0; c < nch; ++c) {
            const size_t ro = (size_t)c*RC;
            gemm_split<0><<<dim3(RC/128, 3), 256, 0, stream>>>(
                y + ro*DD, wqkv_h, wqkv_l, qkv_b + l*384, nullptr, big, 384, 128);
            attn_naive<<<BC*4, 256, 0, stream>>>(big, y + ro*DD);
        }
        gemm_split<2><<<dim3(NROWS/128, 1), 256, 0, stream>>>(
            y, wout_h, wout_l, out_bv + l*128, h, h, 128, 128);
        ln2<<<NROWS, 128, 0, stream>>>(h, ln2_w + l*128, ln2_b + l*128, y);
        for (int c = 0; c < nch; ++c) {
            const size_t ro = (size_t)c*RC;
            gemm_split<1><<<dim3(RC/128, 4), 256, 0, stream>>>(
                y + ro*DD, wf1_h, wf1_l, f1_b + l*512, nullptr, big, 512, 128);
            gemm_split<2><<<dim3(RC/128, 1), 256, 0, stream>>>(
                big, wf2_h, wf2_l, f2_b + l*128, h + ro*DD, h + ro*DD, 128, 512);
        }
    }

    pool_ctx2<<<BB, 128, 0, stream>>>(h, x, sym_id, regime_id, sym_emb, reg_emb,
                                      pool_w, pool_b, ctx_w, ctx_b, ctxf, rv);
    gru2_kernel<<<512, 256, 0, stream>>>(ctxf, gru_wih, gru_bih, gru_whh, gru_bhh,
                                         mu_w1, mu_b1, mu_w2, mu_b2,
                                         vol_w1, vol_b1, vol_w2, vol_b2,
                                         rv, outp);
}

// Round 7
// 2233.755 us; speedup vs baseline: 2.1143x; 2.1143x over previous
//
#include <hip/hip_runtime.h>
#include <math.h>

typedef __bf16 bf16;
typedef __bf16 bf16x8 __attribute__((ext_vector_type(8)));
typedef __bf16 bf16x4 __attribute__((ext_vector_type(4)));
typedef float  floatx4 __attribute__((ext_vector_type(4)));

// dims
#define BB 1024
#define TT 120
#define FF 32
#define DD 128
#define NROWS (BB*TT)      // 122880
#define HOR 90
#define MM 5

// ---------------------------------------------------------------------------
// Encoder weights -> split bf16 pair (hi = bf16(w), lo = bf16(w - hi)).
__global__ __launch_bounds__(256) void prep_weights(
    const float* __restrict__ qkv, const float* __restrict__ outw,
    const float* __restrict__ f1,  const float* __restrict__ f2,
    bf16* __restrict__ dhi, bf16* __restrict__ dlo)
{
    int i = blockIdx.x*256 + threadIdx.x;
    if (i >= 393216) return;
    float v;
    if      (i < 98304)  v = qkv[i];
    else if (i < 131072) v = outw[i - 98304];
    else if (i < 262144) v = f1[i - 131072];
    else                 v = f2[i - 262144];
    bf16 h = (bf16)v;
    dhi[i] = h;
    dlo[i] = (bf16)(v - (float)h);
}

// ---------------------------------------------------------------------------
// Input projection (proven R6). One block (128 thr) per row.
__global__ __launch_bounds__(128) void inproj2(
    const float* __restrict__ x, const int* __restrict__ sym_id,
    const float* __restrict__ sym_emb, const float* __restrict__ in_w,
    const float* __restrict__ in_b, float* __restrict__ h)
{
    __shared__ float xin[48];
    const int row = blockIdx.x;
    const int d   = threadIdx.x;
    const int b   = row / TT;
    const int t   = row % TT;
    if (d < 32)      xin[d] = x[(size_t)row*FF + d];
    else if (d < 48) xin[d] = sym_emb[(size_t)sym_id[b]*16 + (d - 32)];
    __syncthreads();
    float a = in_b[d];
    const float* wr = in_w + (size_t)d*48;
    for (int k = 0; k < 48; ++k) a += xin[k] * wr[k];
    const int di = d & ~1;
    const float f = expf((float)di * (-9.210340371976184f / 128.f));
    const float arg = (float)t * f;
    a += (d & 1) ? cosf(arg) : sinf(arg);
    h[(size_t)row*DD + d] = a;
}

// ---------------------------------------------------------------------------
// LayerNorm (proven R6). One block (128 thr) per row, two-pass variance.
__global__ __launch_bounds__(128) void ln2(
    const float* __restrict__ h, const float* __restrict__ w,
    const float* __restrict__ b, float* __restrict__ y)
{
    __shared__ float red[128];
    __shared__ float mean_s, rstd_s;
    const int row = blockIdx.x;
    const int d = threadIdx.x;
    const float v = h[(size_t)row*DD + d];
    red[d] = v;
    __syncthreads();
    for (int s = 64; s > 0; s >>= 1) {
        if (d < s) red[d] += red[d + s];
        __syncthreads();
    }
    if (d == 0) mean_s = red[0] * (1.f/128.f);
    __syncthreads();
    const float m = mean_s;
    const float dv = v - m;
    red[d] = dv * dv;
    __syncthreads();
    for (int s = 64; s > 0; s >>= 1) {
        if (d < s) red[d] += red[d + s];
        __syncthreads();
    }
    if (d == 0) rstd_s = rsqrtf(red[0] * (1.f/128.f) + 1e-5f);
    __syncthreads();
    y[(size_t)row*DD + d] = dv * rstd_s * w[d] + b[d];
}

// ---------------------------------------------------------------------------
// Split-precision MFMA GEMM (proven).
template<int EPI>
__global__ __launch_bounds__(256) void gemm_split(
    const float* __restrict__ A, const bf16* __restrict__ Whi,
    const bf16* __restrict__ Wlo, const float* __restrict__ bias,
    const float* __restrict__ res, float* __restrict__ outp, int N, int K)
{
    __shared__ alignas(16) bf16 smem[4*128*64];
    bf16* Ah = smem;
    bf16* Al = smem + 8192;
    bf16* Wh = smem + 16384;
    bf16* Wl = smem + 24576;
    const int tid = threadIdx.x;
    const int lane = tid & 63, wave = tid >> 6;
    const int q = lane >> 4, ml = lane & 15;
    const int wm = (wave & 1) * 64, wn = (wave >> 1) * 64;
    const int m0 = blockIdx.x * 128, n0 = blockIdx.y * 128;
    floatx4 acc[4][4];
    #pragma unroll
    for (int i = 0; i < 4; ++i)
        #pragma unroll
        for (int j = 0; j < 4; ++j) acc[i][j] = (floatx4){0.f,0.f,0.f,0.f};
    const int nkb = K >> 6;
    for (int kb = 0; kb < nkb; ++kb) {
        #pragma unroll
        for (int i = 0; i < 4; ++i) {
            int idx = i*256 + tid;
            int r = idx >> 3, c = idx & 7;
            int sw = ((c ^ (r & 7)) * 8);
            {
                const float* ap = A + (size_t)(m0 + r)*K + kb*64 + c*8;
                float4 f0 = *(const float4*)ap;
                float4 f1 = *(const float4*)(ap + 4);
                float v[8] = {f0.x,f0.y,f0.z,f0.w,f1.x,f1.y,f1.z,f1.w};
                bf16x8 hi, lo;
                #pragma unroll
                for (int j = 0; j < 8; ++j) {
                    bf16 hb = (bf16)v[j];
                    hi[j] = hb;
                    lo[j] = (bf16)(v[j] - (float)hb);
                }
                *(bf16x8*)&Ah[r*64 + sw] = hi;
                *(bf16x8*)&Al[r*64 + sw] = lo;
            }
            {
                size_t wo = (size_t)(n0 + r)*K + kb*64 + c*8;
                *(uint4*)&Wh[r*64 + sw] = *(const uint4*)(Whi + wo);
                *(uint4*)&Wl[r*64 + sw] = *(const uint4*)(Wlo + wo);
            }
        }
        __syncthreads();
        #pragma unroll
        for (int s = 0; s < 2; ++s) {
            bf16x8 ah[4], al[4], bh[4], bl[4];
            #pragma unroll
            for (int t = 0; t < 4; ++t) {
                int ra = wm + t*16 + ml;
                int oa = ra*64 + (((s*4+q) ^ (ra & 7))*8);
                ah[t] = *(const bf16x8*)&Ah[oa];
                al[t] = *(const bf16x8*)&Al[oa];
                int rb = wn + t*16 + ml;
                int ob = rb*64 + (((s*4+q) ^ (rb & 7))*8);
                bh[t] = *(const bf16x8*)&Wh[ob];
                bl[t] = *(const bf16x8*)&Wl[ob];
            }
            #pragma unroll
            for (int i = 0; i < 4; ++i)
                #pragma unroll
                for (int j = 0; j < 4; ++j) {
                    acc[i][j] = __builtin_amdgcn_mfma_f32_16x16x32_bf16(ah[i], bh[j], acc[i][j], 0, 0, 0);
                    acc[i][j] = __builtin_amdgcn_mfma_f32_16x16x32_bf16(ah[i], bl[j], acc[i][j], 0, 0, 0);
                    acc[i][j] = __builtin_amdgcn_mfma_f32_16x16x32_bf16(al[i], bh[j], acc[i][j], 0, 0, 0);
                }
        }
        __syncthreads();
    }
    #pragma unroll
    for (int j = 0; j < 4; ++j) {
        int col = n0 + wn + j*16 + ml;
        float bv = bias[col];
        #pragma unroll
        for (int i = 0; i < 4; ++i) {
            #pragma unroll
            for (int r = 0; r < 4; ++r) {
                int row = m0 + wm + i*16 + q*4 + r;
                size_t o = (size_t)row * N + col;
                float v = acc[i][j][r] + bv;
                if      (EPI == 1) v = fmaxf(v, 0.f);
                else if (EPI == 2) v += res[o];
                outp[o] = v;
            }
        }
    }
}

// ---------------------------------------------------------------------------
// Split-precision MFMA attention (R4 version — output-equivalent to the
// naive attention per the R4/R5 bit-identical absmax A/B). One block/(b,h).
__global__ __launch_bounds__(256) void attn_kernel(
    const float* __restrict__ qkv, float* __restrict__ O)
{
    __shared__ alignas(16) bf16 Khi[128*32];
    __shared__ alignas(16) bf16 Klo[128*32];
    __shared__ alignas(16) bf16 Vhi[32*136];
    __shared__ alignas(16) bf16 Vlo[32*136];
    __shared__ alignas(16) bf16 Qhi[32*32];
    __shared__ alignas(16) bf16 Qlo[32*32];
    __shared__ float Sf[32*132];
    const int tid = threadIdx.x, lane = tid & 63, wave = tid >> 6;
    const int q = lane >> 4, ml = lane & 15;
    const int b = blockIdx.x >> 2, hh = blockIdx.x & 3;
    const float* base = qkv + (size_t)b*TT*384 + hh*32;
    #pragma unroll
    for (int i = 0; i < 4; ++i) {
        int idx = i*256 + tid;
        int t = idx >> 3, c = idx & 7;
        float4 kv = {0.f,0.f,0.f,0.f};
        if (t < TT) kv = *(const float4*)(base + (size_t)t*384 + 128 + c*4);
        float v[4] = {kv.x, kv.y, kv.z, kv.w};
        bf16x4 hi, lo;
        #pragma unroll
        for (int j = 0; j < 4; ++j) {
            bf16 hb = (bf16)v[j]; hi[j] = hb; lo[j] = (bf16)(v[j] - (float)hb);
        }
        *(bf16x4*)&Khi[t*32 + c*4] = hi;
        *(bf16x4*)&Klo[t*32 + c*4] = lo;
    }
    #pragma unroll
    for (int i = 0; i < 4; ++i) {
        int idx = i*256 + tid;
        int t = idx >> 3, c = idx & 7;
        float4 vv = {0.f,0.f,0.f,0.f};
        if (t < TT) vv = *(const float4*)(base + (size_t)t*384 + 256 + c*4);
        float v[4] = {vv.x, vv.y, vv.z, vv.w};
        #pragma unroll
        for (int j = 0; j < 4; ++j) {
            bf16 hb = (bf16)v[j];
            Vhi[(c*4 + j)*136 + t] = hb;
            Vlo[(c*4 + j)*136 + t] = (bf16)(v[j] - (float)hb);
        }
    }
    __syncthreads();
    const float scale = 0.17677669529663687f;
    for (int qt = 0; qt < 4; ++qt) {
        {
            int m = tid >> 3, c = tid & 7;
            int t = qt*32 + m;
            float4 qv = {0.f,0.f,0.f,0.f};
            if (t < TT) qv = *(const float4*)(base + (size_t)t*384 + c*4);
            float v[4] = {qv.x, qv.y, qv.z, qv.w};
            bf16x4 hi, lo;
            #pragma unroll
            for (int j = 0; j < 4; ++j) {
                bf16 hb = (bf16)v[j]; hi[j] = hb; lo[j] = (bf16)(v[j] - (float)hb);
            }
            *(bf16x4*)&Qhi[m*32 + c*4] = hi;
            *(bf16x4*)&Qlo[m*32 + c*4] = lo;
        }
        __syncthreads();
        {
            const int mh = wave & 1, nq = wave >> 1;
            int oa = (mh*16 + ml)*32 + q*8;
            bf16x8 ah = *(const bf16x8*)&Qhi[oa];
            bf16x8 al = *(const bf16x8*)&Qlo[oa];
            #pragma unroll
            for (int ni = 0; ni < 4; ++ni) {
                int n0 = nq*64 + ni*16;
                int ob = (n0 + ml)*32 + q*8;
                bf16x8 bh = *(const bf16x8*)&Khi[ob];
                bf16x8 bl = *(const bf16x8*)&Klo[ob];
                floatx4 a4 = (floatx4){0.f,0.f,0.f,0.f};
                a4 = __builtin_amdgcn_mfma_f32_16x16x32_bf16(ah, bh, a4, 0, 0, 0);
                a4 = __builtin_amdgcn_mfma_f32_16x16x32_bf16(ah, bl, a4, 0, 0, 0);
                a4 = __builtin_amdgcn_mfma_f32_16x16x32_bf16(al, bh, a4, 0, 0, 0);
                #pragma unroll
                for (int r = 0; r < 4; ++r)
                    Sf[(mh*16 + q*4 + r)*132 + n0 + ml] = a4[r]*scale;
            }
        }
        __syncthreads();
        #pragma unroll
        for (int i = 0; i < 8; ++i) {
            int rl = wave*8 + i;
            int rg = qt*32 + rl;
            if (rg < TT) {
                float v0 = Sf[rl*132 + lane];
                bool ok1 = (lane + 64) < TT;
                float v1 = ok1 ? Sf[rl*132 + lane + 64] : -3e38f;
                float mx = fmaxf(v0, v1);
                #pragma unroll
                for (int o = 1; o < 64; o <<= 1) mx = fmaxf(mx, __shfl_xor(mx, o));
                float e0 = expf(v0 - mx);
                float e1 = ok1 ? expf(v1 - mx) : 0.f;
                float sm = e0 + e1;
                #pragma unroll
                for (int o = 1; o < 64; o <<= 1) sm += __shfl_xor(sm, o);
                float inv = 1.f / sm;
                Sf[rl*132 + lane]      = e0 * inv;
                Sf[rl*132 + lane + 64] = e1 * inv;
            }
        }
        __syncthreads();
        {
            const int mt = wave & 1, nt = wave >> 1;
            floatx4 a4 = (floatx4){0.f,0.f,0.f,0.f};
            #pragma unroll
            for (int s = 0; s < 4; ++s) {
                const float* pr = &Sf[(mt*16 + ml)*132 + s*32 + q*8];
                float4 p0 = *(const float4*)pr;
                float4 p1 = *(const float4*)(pr + 4);
                float pv[8] = {p0.x,p0.y,p0.z,p0.w,p1.x,p1.y,p1.z,p1.w};
                bf16x8 ph, pl;
                #pragma unroll
                for (int j = 0; j < 8; ++j) {
                    bf16 hb = (bf16)pv[j]; ph[j] = hb; pl[j] = (bf16)(pv[j] - (float)hb);
                }
                int ov = (nt*16 + ml)*136 + s*32 + q*8;
                bf16x8 vh = *(const bf16x8*)&Vhi[ov];
                bf16x8 vl = *(const bf16x8*)&Vlo[ov];
                a4 = __builtin_amdgcn_mfma_f32_16x16x32_bf16(ph, vh, a4, 0, 0, 0);
                a4 = __builtin_amdgcn_mfma_f32_16x16x32_bf16(ph, vl, a4, 0, 0, 0);
                a4 = __builtin_amdgcn_mfma_f32_16x16x32_bf16(pl, vh, a4, 0, 0, 0);
            }
            #pragma unroll
            for (int r = 0; r < 4; ++r) {
                int row = qt*32 + mt*16 + q*4 + r;
                if (row < TT)
                    O[((size_t)b*TT + row)*DD + hh*32 + nt*16 + ml] = a4[r];
            }
        }
        __syncthreads();
    }
}

// ---------------------------------------------------------------------------
// Pool+ctx+rv (proven R5/R6).
__global__ __launch_bounds__(128) void pool_ctx2(
    const float* __restrict__ h, const float* __restrict__ x,
    const int* __restrict__ sym_id, const int* __restrict__ regime_id,
    const float* __restrict__ sym_emb, const float* __restrict__ reg_emb,
    const float* __restrict__ pool_w, const float* __restrict__ pool_b,
    const float* __restrict__ ctx_w, const float* __restrict__ ctx_b,
    float* __restrict__ ctxf, float* __restrict__ rv)
{
    __shared__ float aw[120];
    __shared__ float cat[152];
    const int b = blockIdx.x;
    const int tid = threadIdx.x;
    const float* hb = h + (size_t)b*TT*DD;
    if (tid < 120) {
        float s = pool_b[0];
        for (int k = 0; k < 128; ++k) s += hb[(size_t)tid*DD + k] * pool_w[k];
        aw[tid] = s;
    }
    __syncthreads();
    if (tid == 0) {
        float mx = -3e38f;
        for (int t = 0; t < TT; ++t) mx = fmaxf(mx, aw[t]);
        float sm = 0.f;
        for (int t = 0; t < TT; ++t) { float e = expf(aw[t]-mx); aw[t] = e; sm += e; }
        float inv = 1.f/sm;
        for (int t = 0; t < TT; ++t) aw[t] *= inv;
    } else if (tid == 64) {
        float s = 0.f;
        for (int t = 0; t < TT; ++t) s += x[((size_t)b*TT + t)*FF];
        float mean = s / 120.f;
        float ss = 0.f;
        for (int t = 0; t < TT; ++t) {
            float d0 = x[((size_t)b*TT + t)*FF] - mean;
            ss += d0*d0;
        }
        rv[b] = sqrtf(ss / 119.f);
    }
    __syncthreads();
    {
        float p = 0.f;
        for (int t = 0; t < TT; ++t) p += aw[t] * hb[(size_t)t*DD + tid];
        cat[tid] = p;
    }
    if (tid < 16)      cat[128 + tid] = sym_emb[(size_t)sym_id[b]*16 + tid];
    else if (tid < 24) cat[144 + (tid-16)] = reg_emb[regime_id[b]*8 + (tid-16)];
    __syncthreads();
    float acc = ctx_b[tid];
    const float* wr = ctx_w + (size_t)tid*152;
    for (int j = 0; j < 152; ++j) acc += cat[j] * wr[j];
    ctxf[(size_t)b*128 + tid] = acc;
}

// ---------------------------------------------------------------------------
// MFMA GRU decoder: 64 blocks x 16 rows x 256 threads (4 waves), persistent.
// whh and head-w1 held in registers as split hi/lo MFMA B-fragments; hd in
// LDS fp32 with on-the-fly hi/lo A-frag conversion. Split product
// AhBh+AhBl+AlBh == fp32-grade (same scheme as proven gemm_split).
__global__ __launch_bounds__(256, 1) void gru3_kernel(
    const float* __restrict__ ctxf, const float* __restrict__ wih,
    const float* __restrict__ bih, const float* __restrict__ whh,
    const float* __restrict__ bhh,
    const float* __restrict__ mu_w1, const float* __restrict__ mu_b1,
    const float* __restrict__ mu_w2, const float* __restrict__ mu_b2,
    const float* __restrict__ vol_w1, const float* __restrict__ vol_b1,
    const float* __restrict__ vol_w2, const float* __restrict__ vol_b2,
    const float* __restrict__ rv, float* __restrict__ out)
{
    __shared__ float hd_s[16*132];
    __shared__ float gh_s[16*388];
    __shared__ float gi_s[16*388];
    __shared__ float g1_s[16*132];
    __shared__ float wih5_s[384*5];
    __shared__ float bhh_s[384];
    __shared__ float w2m_s[5*64];
    __shared__ float w2v_s[5*64];
    __shared__ float step_s[16*5];
    __shared__ float rvv[16];
    const int tid = threadIdx.x, lane = tid & 63, wave = tid >> 6;
    const int q = lane >> 4, ml = lane & 15;
    const int r0 = blockIdx.x * 16;

    // ---- load recurrent + head weights into registers as split fragments
    bf16x8 wbh1[6][4], wbl1[6][4], wbh2[2][4], wbl2[2][4];
    float bias2[2];
    #pragma unroll
    for (int t = 0; t < 6; ++t)
        #pragma unroll
        for (int s = 0; s < 4; ++s) {
            int n = wave*96 + t*16 + ml;
            const float* wp = whh + (size_t)n*128 + s*32 + q*8;
            float4 f0 = *(const float4*)wp;
            float4 f1 = *(const float4*)(wp + 4);
            float v[8] = {f0.x,f0.y,f0.z,f0.w,f1.x,f1.y,f1.z,f1.w};
            bf16x8 hi, lo;
            #pragma unroll
            for (int j = 0; j < 8; ++j) {
                bf16 hb = (bf16)v[j]; hi[j] = hb; lo[j] = (bf16)(v[j] - (float)hb);
            }
            wbh1[t][s] = hi; wbl1[t][s] = lo;
        }
    #pragma unroll
    for (int t = 0; t < 2; ++t) {
        int n2 = wave*32 + t*16 + ml;
        bias2[t] = (n2 < 64) ? mu_b1[n2] : vol_b1[n2 - 64];
        #pragma unroll
        for (int s = 0; s < 4; ++s) {
            const float* wp = ((n2 < 64) ? (mu_w1 + (size_t)n2*128)
                                         : (vol_w1 + (size_t)(n2-64)*128)) + s*32 + q*8;
            float4 f0 = *(const float4*)wp;
            float4 f1 = *(const float4*)(wp + 4);
            float v[8] = {f0.x,f0.y,f0.z,f0.w,f1.x,f1.y,f1.z,f1.w};
            bf16x8 hi, lo;
            #pragma unroll
            for (int j = 0; j < 8; ++j) {
                bf16 hb = (bf16)v[j]; hi[j] = hb; lo[j] = (bf16)(v[j] - (float)hb);
            }
            wbh2[t][s] = hi; wbl2[t][s] = lo;
        }
    }

    // ---- init LDS state
    for (int i = tid; i < 2048; i += 256)
        hd_s[(i>>7)*132 + (i&127)] = ctxf[(size_t)r0*128 + i];
    for (int i = tid; i < 1920; i += 256) wih5_s[i] = wih[(i/5)*133 + (i%5)];
    for (int i = tid; i < 384; i += 256) bhh_s[i] = bhh[i];
    for (int i = tid; i < 320; i += 256) { w2m_s[i] = mu_w2[i]; w2v_s[i] = vol_w2[i]; }
    if (tid < 80) step_s[tid] = 0.f;
    if (tid < 16) rvv[tid] = 1.f + rv[r0 + tid];
    __syncthreads();
    // gi = bih + ctx @ wih[:,5:]^T  (fp32, one-time)
    for (int ii = 0; ii < 24; ++ii) {
        int idx = ii*256 + tid;
        int rr = idx / 384, n = idx % 384;
        const float* wr = wih + (size_t)n*133 + 5;
        float a = bih[n];
        for (int k = 0; k < 128; ++k) a += hd_s[rr*132 + k] * wr[k];
        gi_s[rr*388 + n] = a;
    }
    __syncthreads();

    for (int st = 0; st < HOR; ++st) {
        // ---- phase 1: gh = hd @ whh^T (split MFMA)
        {
            bf16x8 ah[4], al[4];
            #pragma unroll
            for (int s = 0; s < 4; ++s) {
                const float* p = &hd_s[ml*132 + s*32 + q*8];
                float4 f0 = *(const float4*)p;
                float4 f1 = *(const float4*)(p + 4);
                float v[8] = {f0.x,f0.y,f0.z,f0.w,f1.x,f1.y,f1.z,f1.w};
                bf16x8 hi, lo;
                #pragma unroll
                for (int j = 0; j < 8; ++j) {
                    bf16 hb = (bf16)v[j]; hi[j] = hb; lo[j] = (bf16)(v[j] - (float)hb);
                }
                ah[s] = hi; al[s] = lo;
            }
            #pragma unroll
            for (int t = 0; t < 6; ++t) {
                floatx4 a4 = (floatx4){0.f,0.f,0.f,0.f};
                #pragma unroll
                for (int s = 0; s < 4; ++s) {
                    a4 = __builtin_amdgcn_mfma_f32_16x16x32_bf16(ah[s], wbh1[t][s], a4, 0, 0, 0);
                    a4 = __builtin_amdgcn_mfma_f32_16x16x32_bf16(ah[s], wbl1[t][s], a4, 0, 0, 0);
                    a4 = __builtin_amdgcn_mfma_f32_16x16x32_bf16(al[s], wbh1[t][s], a4, 0, 0, 0);
                }
                #pragma unroll
                for (int r = 0; r < 4; ++r)
                    gh_s[(q*4+r)*388 + wave*96 + t*16 + ml] = a4[r];
            }
        }
        __syncthreads();
        // ---- phase 2: gates (fp32 VALU), update hd
        #pragma unroll
        for (int i = 0; i < 8; ++i) {
            int idx = i*256 + tid;
            int rr = idx >> 7, d = idx & 127;
            float ir = gi_s[rr*388 + d];
            float iz = gi_s[rr*388 + 128 + d];
            float in_ = gi_s[rr*388 + 256 + d];
            #pragma unroll
            for (int j = 0; j < 5; ++j) {
                float sv = step_s[rr*5 + j];
                ir  += sv * wih5_s[d*5 + j];
                iz  += sv * wih5_s[(128+d)*5 + j];
                in_ += sv * wih5_s[(256+d)*5 + j];
            }
            float hr = gh_s[rr*388 + d]       + bhh_s[d];
            float hz = gh_s[rr*388 + 128 + d] + bhh_s[128 + d];
            float hn = gh_s[rr*388 + 256 + d] + bhh_s[256 + d];
            float rg = 1.f/(1.f + expf(-(ir + hr)));
            float zg = 1.f/(1.f + expf(-(iz + hz)));
            float nn = tanhf(in_ + rg*hn);
            hd_s[rr*132 + d] = (1.f - zg)*nn + zg*hd_s[rr*132 + d];
        }
        __syncthreads();
        // ---- phase 3: head pre-acts (split MFMA) + erf-GELU
        {
            bf16x8 ah[4], al[4];
            #pragma unroll
            for (int s = 0; s < 4; ++s) {
                const float* p = &hd_s[ml*132 + s*32 + q*8];
                float4 f0 = *(const float4*)p;
                float4 f1 = *(const float4*)(p + 4);
                float v[8] = {f0.x,f0.y,f0.z,f0.w,f1.x,f1.y,f1.z,f1.w};
                bf16x8 hi, lo;
                #pragma unroll
                for (int j = 0; j < 8; ++j) {
                    bf16 hb = (bf16)v[j]; hi[j] = hb; lo[j] = (bf16)(v[j] - (float)hb);
                }
                ah[s] = hi; al[s] = lo;
            }
            #pragma unroll
            for (int t = 0; t < 2; ++t) {
                floatx4 a4 = (floatx4){0.f,0.f,0.f,0.f};
                #pragma unroll
                for (int s = 0; s < 4; ++s) {
                    a4 = __builtin_amdgcn_mfma_f32_16x16x32_bf16(ah[s], wbh2[t][s], a4, 0, 0, 0);
                    a4 = __builtin_amdgcn_mfma_f32_16x16x32_bf16(ah[s], wbl2[t][s], a4, 0, 0, 0);
                    a4 = __builtin_amdgcn_mfma_f32_16x16x32_bf16(al[s], wbh2[t][s], a4, 0, 0, 0);
                }
                int n2 = wave*32 + t*16 + ml;
                #pragma unroll
                for (int r = 0; r < 4; ++r) {
                    float u = a4[r] + bias2[t];
                    g1_s[(q*4+r)*132 + n2] = 0.5f*u*(1.f + erff(u*0.70710678118654752f));
                }
            }
        }
        __syncthreads();
        // ---- phase 4: w2 heads + pred + step update
        if (tid < 80) {
            int rr = tid / 5, o = tid % 5;
            float am = mu_b2[o], av = vol_b2[o];
            const float* g1r = &g1_s[rr*132];
            #pragma unroll 8
            for (int j = 0; j < 64; ++j) {
                am += g1r[j]      * w2m_s[o*64 + j];
                av += g1r[64 + j] * w2v_s[o*64 + j];
            }
            float mu = tanhf(am);
            float sp = (av > 20.f) ? av : log1pf(expf(av));
            float pr = mu * sp * rvv[rr];
            step_s[tid] = pr;
            out[((size_t)(r0 + rr)*HOR + st)*MM + o] = pr;
        }
        __syncthreads();
    }
}

// ---------------------------------------------------------------------------
extern "C" void kernel_launch(void* const* d_in, const int* in_sizes, int n_in,
                              void* d_out, int out_size, void* d_ws, size_t ws_size,
                              hipStream_t stream)
{
    (void)in_sizes; (void)n_in; (void)out_size;
    const float* x        = (const float*)d_in[0];
    const int*   sym_id   = (const int*)d_in[1];
    const int*   regime_id= (const int*)d_in[2];
    const float* sym_emb  = (const float*)d_in[3];
    const float* reg_emb  = (const float*)d_in[4];
    const float* in_w     = (const float*)d_in[5];
    const float* in_b     = (const float*)d_in[6];
    const float* qkv_w    = (const float*)d_in[7];
    const float* qkv_b    = (const float*)d_in[8];
    const float* out_w    = (const float*)d_in[9];
    const float* out_bv   = (const float*)d_in[10];
    const float* ln1_w    = (const float*)d_in[11];
    const float* ln1_b    = (const float*)d_in[12];
    const float* ln2_w    = (const float*)d_in[13];
    const float* ln2_b    = (const float*)d_in[14];
    const float* f1_w     = (const float*)d_in[15];
    const float* f1_b     = (const float*)d_in[16];
    const float* f2_w     = (const float*)d_in[17];
    const float* f2_b     = (const float*)d_in[18];
    const float* pool_w   = (const float*)d_in[19];
    const float* pool_b   = (const float*)d_in[20];
    const float* ctx_w    = (const float*)d_in[21];
    const float* ctx_b    = (const float*)d_in[22];
    const float* gru_wih  = (const float*)d_in[23];
    const float* gru_whh  = (const float*)d_in[24];
    const float* gru_bih  = (const float*)d_in[25];
    const float* gru_bhh  = (const float*)d_in[26];
    const float* mu_w1    = (const float*)d_in[27];
    const float* mu_b1    = (const float*)d_in[28];
    const float* mu_w2    = (const float*)d_in[29];
    const float* mu_b2    = (const float*)d_in[30];
    const float* vol_w1   = (const float*)d_in[31];
    const float* vol_b1   = (const float*)d_in[32];
    const float* vol_w2   = (const float*)d_in[33];
    const float* vol_b2   = (const float*)d_in[34];
    float* outp = (float*)d_out;

    char* ws = (char*)d_ws;
    size_t off = 0;
    auto alloc = [&](size_t bytes) -> void* {
        void* p = ws + off;
        off = (off + bytes + 255) & ~(size_t)255;
        return p;
    };
    float* h    = (float*)alloc((size_t)NROWS*DD*4);        // 62.9 MB
    float* y    = (float*)alloc((size_t)NROWS*DD*4);        // 62.9 MB
    bf16*  whi  = (bf16*) alloc((size_t)393216*2);
    bf16*  wlo  = (bf16*) alloc((size_t)393216*2);
    float* ctxf = (float*)alloc((size_t)BB*DD*4);
    float* rv   = (float*)alloc((size_t)BB*4);
    size_t avail = (ws_size > off) ? (ws_size - off) : 0;
    int nch;
    if      (avail >= (size_t)NROWS*512*4)     nch = 1;
    else if (avail >= (size_t)NROWS/2*512*4)   nch = 2;
    else                                       nch = 4;
    const int RC = NROWS / nch;
    const int BC = BB / nch;
    float* big = (float*)(ws + off);

    prep_weights<<<1536, 256, 0, stream>>>(qkv_w, out_w, f1_w, f2_w, whi, wlo);
    inproj2<<<NROWS, 128, 0, stream>>>(x, sym_id, sym_emb, in_w, in_b, h);

    for (int l = 0; l < 2; ++l) {
        const bf16* wqkv_h = whi + l*49152;          const bf16* wqkv_l = wlo + l*49152;
        const bf16* wout_h = whi + 98304 + l*16384;  const bf16* wout_l = wlo + 98304 + l*16384;
        const bf16* wf1_h  = whi + 131072 + l*65536; const bf16* wf1_l  = wlo + 131072 + l*65536;
        const bf16* wf2_h  = whi + 262144 + l*65536; const bf16* wf2_l  = wlo + 262144 + l*65536;
        ln2<<<NROWS, 128, 0, stream>>>(h, ln1_w + l*128, ln1_b + l*128, y);
        for (int c = 0; c < nch; ++c) {
            const size_t ro = (size_t)c*RC;
            gemm_split<0><<<dim3(RC/128, 3), 256, 0, stream>>>(
                y + ro*DD, wqkv_h, wqkv_l, qkv_b + l*384, nullptr, big, 384, 128);
            attn_kernel<<<BC*4, 256, 0, stream>>>(big, y + ro*DD);
        }
        gemm_split<2><<<dim3(NROWS/128, 1), 256, 0, stream>>>(
            y, wout_h, wout_l, out_bv + l*128, h, h, 128, 128);
        ln2<<<NROWS, 128, 0, stream>>>(h, ln2_w + l*128, ln2_b + l*128, y);
        for (int c = 0; c < nch; ++c) {
            const size_t ro = (size_t)c*RC;
            gemm_split<1><<<dim3(RC/128, 4), 256, 0, stream>>>(
                y + ro*DD, wf1_h, wf1_l, f1_b + l*512, nullptr, big, 512, 128);
            gemm_split<2><<<dim3(RC/128, 1), 256, 0, stream>>>(
                big, wf2_h, wf2_l, f2_b + l*128, h + ro*DD, h + ro*DD, 128, 512);
        }
    }

    pool_ctx2<<<BB, 128, 0, stream>>>(h, x, sym_id, regime_id, sym_emb, reg_emb,
                                      pool_w, pool_b, ctx_w, ctx_b, ctxf, rv);
    gru3_kernel<<<64, 256, 0, stream>>>(ctxf, gru_wih, gru_bih, gru_whh, gru_bhh,
                                        mu_w1, mu_b1, mu_w2, mu_b2,
                                        vol_w1, vol_b1, vol_w2, vol_b2,
                                        rv, outp);
}

// Round 8
// 1751.488 us; speedup vs baseline: 2.6965x; 1.2753x over previous
//
#include <hip/hip_runtime.h>
#include <math.h>

typedef __bf16 bf16;
typedef __bf16 bf16x8 __attribute__((ext_vector_type(8)));
typedef __bf16 bf16x2 __attribute__((ext_vector_type(2)));
typedef float  floatx4 __attribute__((ext_vector_type(4)));

// dims
#define BB 1024
#define TT 120
#define FF 32
#define DD 128
#define NROWS (BB*TT)      // 122880
#define HOR 90
#define MM 5

__device__ __forceinline__ float fast_sigmoid(float x) {
    x = fminf(fmaxf(x, -30.f), 30.f);
    return 1.f / (1.f + __expf(-x));
}
__device__ __forceinline__ float fast_tanh(float x) {
    x = fminf(fmaxf(x, -15.f), 15.f);
    float e = __expf(-2.f * x);
    return (1.f - e) / (1.f + e);
}

// ---------------------------------------------------------------------------
// Encoder weights -> bf16 (single precision path; exonerated in R2).
__global__ __launch_bounds__(256) void prep_weights(
    const float* __restrict__ qkv, const float* __restrict__ outw,
    const float* __restrict__ f1,  const float* __restrict__ f2,
    bf16* __restrict__ dst)
{
    int i = blockIdx.x*256 + threadIdx.x;
    if (i >= 393216) return;
    float v;
    if      (i < 98304)  v = qkv[i];
    else if (i < 131072) v = outw[i - 98304];
    else if (i < 262144) v = f1[i - 131072];
    else                 v = f2[i - 262144];
    dst[i] = (bf16)v;
}

// ---------------------------------------------------------------------------
// Input projection (proven R6). One block (128 thr) per row. fp32 out.
__global__ __launch_bounds__(128) void inproj2(
    const float* __restrict__ x, const int* __restrict__ sym_id,
    const float* __restrict__ sym_emb, const float* __restrict__ in_w,
    const float* __restrict__ in_b, float* __restrict__ h)
{
    __shared__ float xin[48];
    const int row = blockIdx.x;
    const int d   = threadIdx.x;
    const int b   = row / TT;
    const int t   = row % TT;
    if (d < 32)      xin[d] = x[(size_t)row*FF + d];
    else if (d < 48) xin[d] = sym_emb[(size_t)sym_id[b]*16 + (d - 32)];
    __syncthreads();
    float a = in_b[d];
    const float* wr = in_w + (size_t)d*48;
    for (int k = 0; k < 48; ++k) a += xin[k] * wr[k];
    const int di = d & ~1;
    const float f = expf((float)di * (-9.210340371976184f / 128.f));
    const float arg = (float)t * f;
    a += (d & 1) ? cosf(arg) : sinf(arg);
    h[(size_t)row*DD + d] = a;
}

// ---------------------------------------------------------------------------
// LayerNorm (proven R6 algorithm), bf16 output. One block (128 thr) per row.
__global__ __launch_bounds__(128) void ln2b(
    const float* __restrict__ h, const float* __restrict__ w,
    const float* __restrict__ b, bf16* __restrict__ y)
{
    __shared__ float red[128];
    __shared__ float mean_s, rstd_s;
    const int row = blockIdx.x;
    const int d = threadIdx.x;
    const float v = h[(size_t)row*DD + d];
    red[d] = v;
    __syncthreads();
    for (int s = 64; s > 0; s >>= 1) {
        if (d < s) red[d] += red[d + s];
        __syncthreads();
    }
    if (d == 0) mean_s = red[0] * (1.f/128.f);
    __syncthreads();
    const float m = mean_s;
    const float dv = v - m;
    red[d] = dv * dv;
    __syncthreads();
    for (int s = 64; s > 0; s >>= 1) {
        if (d < s) red[d] += red[d + s];
        __syncthreads();
    }
    if (d == 0) rstd_s = rsqrtf(red[0] * (1.f/128.f) + 1e-5f);
    __syncthreads();
    y[(size_t)row*DD + d] = (bf16)(dv * rstd_s * w[d] + b[d]);
}

// ---------------------------------------------------------------------------
// bf16 MFMA GEMM (R2 version — exonerated): out = A[M,K] @ W[N,K]^T + bias.
// EPI: 0 bias->bf16, 1 bias+relu->bf16, 2 bias+residual->f32
__global__ __launch_bounds__(256) void gemm_kernel_0(
    const bf16* A, const bf16* W, const float* bias, const float* res,
    void* outp, int N, int K);

template<int EPI>
__global__ __launch_bounds__(256) void gemm_kernel(
    const bf16* __restrict__ A, const bf16* __restrict__ W,
    const float* __restrict__ bias, const float* __restrict__ res,
    void* __restrict__ outp, int N, int K)
{
    __shared__ alignas(16) bf16 As[128*128];
    __shared__ alignas(16) bf16 Ws[128*128];
    const int tid = threadIdx.x;
    const int lane = tid & 63, wave = tid >> 6;
    const int q = lane >> 4, ml = lane & 15;
    const int wm = (wave & 1) * 64, wn = (wave >> 1) * 64;
    const int m0 = blockIdx.x * 128, n0 = blockIdx.y * 128;
    floatx4 acc[4][4];
    #pragma unroll
    for (int i = 0; i < 4; ++i)
        #pragma unroll
        for (int j = 0; j < 4; ++j) acc[i][j] = (floatx4){0.f,0.f,0.f,0.f};
    const int nkb = K >> 7;
    for (int kb = 0; kb < nkb; ++kb) {
        #pragma unroll
        for (int i = 0; i < 8; ++i) {
            int idx = i*256 + tid;
            int r = idx >> 4, cc = idx & 15;
            uint4 va = *(const uint4*)(A + (size_t)(m0 + r)*K + kb*128 + cc*8);
            *(uint4*)&As[r*128 + ((cc ^ (r & 15))*8)] = va;
            uint4 vw = *(const uint4*)(W + (size_t)(n0 + r)*K + kb*128 + cc*8);
            *(uint4*)&Ws[r*128 + ((cc ^ (r & 15))*8)] = vw;
        }
        __syncthreads();
        #pragma unroll
        for (int s = 0; s < 4; ++s) {
            bf16x8 af[4], bfr[4];
            #pragma unroll
            for (int t = 0; t < 4; ++t) {
                int ra = wm + t*16 + ml;
                af[t]  = *(const bf16x8*)&As[ra*128 + (((4*s+q) ^ (ra & 15))*8)];
                int rb = wn + t*16 + ml;
                bfr[t] = *(const bf16x8*)&Ws[rb*128 + (((4*s+q) ^ (rb & 15))*8)];
            }
            #pragma unroll
            for (int i = 0; i < 4; ++i)
                #pragma unroll
                for (int j = 0; j < 4; ++j)
                    acc[i][j] = __builtin_amdgcn_mfma_f32_16x16x32_bf16(af[i], bfr[j], acc[i][j], 0, 0, 0);
        }
        __syncthreads();
    }
    #pragma unroll
    for (int j = 0; j < 4; ++j) {
        int col = n0 + wn + j*16 + ml;
        float bv = bias[col];
        #pragma unroll
        for (int i = 0; i < 4; ++i) {
            #pragma unroll
            for (int r = 0; r < 4; ++r) {
                int row = m0 + wm + i*16 + q*4 + r;
                size_t o = (size_t)row * N + col;
                float v = acc[i][j][r] + bv;
                if      (EPI == 0) ((bf16*)outp)[o] = (bf16)v;
                else if (EPI == 1) ((bf16*)outp)[o] = (bf16)fmaxf(v, 0.f);
                else               ((float*)outp)[o] = v + res[o];
            }
        }
    }
}

// ---------------------------------------------------------------------------
// bf16 MFMA attention (R2 version — exonerated). One block per (b,h).
// qkv bf16 [chunk_rows,384] -> O bf16 [chunk_rows,128].
__global__ __launch_bounds__(256) void attn_b16(
    const bf16* __restrict__ qkv, bf16* __restrict__ O)
{
    __shared__ alignas(16) bf16 Qs[128*32];
    __shared__ alignas(16) bf16 Ks[128*32];
    __shared__ alignas(16) bf16 VT[32*128];
    __shared__ float Sf[64*132];
    const int tid = threadIdx.x, lane = tid & 63, wave = tid >> 6;
    const int q = lane >> 4, ml = lane & 15;
    const int b = blockIdx.x >> 2, hh = blockIdx.x & 3;
    const bf16* base = qkv + (size_t)b*TT*384 + hh*32;
    #pragma unroll
    for (int i = 0; i < 2; ++i) {
        int idx = i*256 + tid;
        int r = idx >> 2, cc = idx & 3;
        uint4 vq = {0,0,0,0}, vk = {0,0,0,0};
        if (r < TT) {
            vq = *(const uint4*)(base + (size_t)r*384 + cc*8);
            vk = *(const uint4*)(base + (size_t)r*384 + 128 + cc*8);
        }
        int cs = cc ^ ((r >> 1) & 3);
        *(uint4*)&Qs[r*32 + cs*8] = vq;
        *(uint4*)&Ks[r*32 + cs*8] = vk;
    }
    #pragma unroll
    for (int i = 0; i < 16; ++i) {           // V transposed, pad zeroed
        int idx = i*256 + tid;
        int t = idx >> 5, e = idx & 31;
        bf16 v = (bf16)0.f;
        if (t < TT) v = base[(size_t)t*384 + 256 + e];
        VT[e*128 + (((t >> 3) ^ (e & 15))*8) + (t & 7)] = v;
    }
    __syncthreads();
    const float scale = 0.17677669529663687f;   // 1/sqrt(32)
    for (int hf = 0; hf < 2; ++hf) {
        {
            int rowa = hf*64 + wave*16 + ml;
            bf16x8 af = *(const bf16x8*)&Qs[rowa*32 + ((q ^ ((rowa>>1)&3))*8)];
            #pragma unroll
            for (int ni = 0; ni < 8; ++ni) {
                int rowb = ni*16 + ml;
                bf16x8 bfr = *(const bf16x8*)&Ks[rowb*32 + ((q ^ ((rowb>>1)&3))*8)];
                floatx4 a4 = __builtin_amdgcn_mfma_f32_16x16x32_bf16(
                    af, bfr, (floatx4){0.f,0.f,0.f,0.f}, 0, 0, 0);
                #pragma unroll
                for (int r = 0; r < 4; ++r)
                    Sf[(wave*16 + q*4 + r)*132 + ni*16 + ml] = a4[r]*scale;
            }
        }
        __syncthreads();
        for (int i = 0; i < 16; ++i) {
            int rl = wave*16 + i;
            int rg = hf*64 + rl;
            if (rg < TT) {
                float v0 = Sf[rl*132 + lane];
                bool ok1 = (lane + 64) < TT;
                float v1 = ok1 ? Sf[rl*132 + lane + 64] : -3e38f;
                float mx = fmaxf(v0, v1);
                #pragma unroll
                for (int o = 1; o < 64; o <<= 1) mx = fmaxf(mx, __shfl_xor(mx, o));
                float e0 = expf(v0 - mx);
                float e1 = ok1 ? expf(v1 - mx) : 0.f;
                float sm = e0 + e1;
                #pragma unroll
                for (int o = 1; o < 64; o <<= 1) sm += __shfl_xor(sm, o);
                float inv = 1.f / sm;
                Sf[rl*132 + lane]      = e0 * inv;
                Sf[rl*132 + lane + 64] = e1 * inv;
            }
        }
        __syncthreads();
        floatx4 pacc[2];
        pacc[0] = (floatx4){0.f,0.f,0.f,0.f};
        pacc[1] = (floatx4){0.f,0.f,0.f,0.f};
        #pragma unroll
        for (int s = 0; s < 4; ++s) {
            const float* pr = &Sf[(wave*16 + ml)*132 + 32*s + 8*q];
            float4 p0 = *(const float4*)pr;
            float4 p1 = *(const float4*)(pr + 4);
            bf16x8 af2 = {(bf16)p0.x,(bf16)p0.y,(bf16)p0.z,(bf16)p0.w,
                          (bf16)p1.x,(bf16)p1.y,(bf16)p1.z,(bf16)p1.w};
            #pragma unroll
            for (int nv = 0; nv < 2; ++nv) {
                int e = nv*16 + ml;
                bf16x8 bfr = *(const bf16x8*)&VT[e*128 + ((((4*s+q) ^ (e & 15)))*8)];
                pacc[nv] = __builtin_amdgcn_mfma_f32_16x16x32_bf16(af2, bfr, pacc[nv], 0, 0, 0);
            }
        }
        #pragma unroll
        for (int nv = 0; nv < 2; ++nv)
            #pragma unroll
            for (int r = 0; r < 4; ++r) {
                int row = hf*64 + wave*16 + q*4 + r;
                if (row < TT)
                    O[((size_t)b*TT + row)*DD + hh*32 + nv*16 + ml] = (bf16)pacc[nv][r];
            }
        __syncthreads();
    }
}

// ---------------------------------------------------------------------------
// Pool+ctx+rv (proven R5/R6).
__global__ __launch_bounds__(128) void pool_ctx2(
    const float* __restrict__ h, const float* __restrict__ x,
    const int* __restrict__ sym_id, const int* __restrict__ regime_id,
    const float* __restrict__ sym_emb, const float* __restrict__ reg_emb,
    const float* __restrict__ pool_w, const float* __restrict__ pool_b,
    const float* __restrict__ ctx_w, const float* __restrict__ ctx_b,
    float* __restrict__ ctxf, float* __restrict__ rv)
{
    __shared__ float aw[120];
    __shared__ float cat[152];
    const int b = blockIdx.x;
    const int tid = threadIdx.x;
    const float* hb = h + (size_t)b*TT*DD;
    if (tid < 120) {
        float s = pool_b[0];
        for (int k = 0; k < 128; ++k) s += hb[(size_t)tid*DD + k] * pool_w[k];
        aw[tid] = s;
    }
    __syncthreads();
    if (tid == 0) {
        float mx = -3e38f;
        for (int t = 0; t < TT; ++t) mx = fmaxf(mx, aw[t]);
        float sm = 0.f;
        for (int t = 0; t < TT; ++t) { float e = expf(aw[t]-mx); aw[t] = e; sm += e; }
        float inv = 1.f/sm;
        for (int t = 0; t < TT; ++t) aw[t] *= inv;
    } else if (tid == 64) {
        float s = 0.f;
        for (int t = 0; t < TT; ++t) s += x[((size_t)b*TT + t)*FF];
        float mean = s / 120.f;
        float ss = 0.f;
        for (int t = 0; t < TT; ++t) {
            float d0 = x[((size_t)b*TT + t)*FF] - mean;
            ss += d0*d0;
        }
        rv[b] = sqrtf(ss / 119.f);
    }
    __syncthreads();
    {
        float p = 0.f;
        for (int t = 0; t < TT; ++t) p += aw[t] * hb[(size_t)t*DD + tid];
        cat[tid] = p;
    }
    if (tid < 16)      cat[128 + tid] = sym_emb[(size_t)sym_id[b]*16 + tid];
    else if (tid < 24) cat[144 + (tid-16)] = reg_emb[regime_id[b]*8 + (tid-16)];
    __syncthreads();
    float acc = ctx_b[tid];
    const float* wr = ctx_w + (size_t)tid*152;
    for (int j = 0; j < 152; ++j) acc += cat[j] * wr[j];
    ctxf[(size_t)b*128 + tid] = acc;
}

// ---------------------------------------------------------------------------
// GRU decoder v4: 64 blocks x 16 rows x 512 threads (8 waves), persistent.
// - wave w owns cols [w*16,(w+1)*16): the r/z/n gate tiles land in the SAME
//   lane's accumulators -> gates fused in-register (no gh LDS round-trip).
// - hd kept as hi/lo bf16 in LDS, double-buffered (no read/write race,
//   A-fragments load directly with zero conversion).
// - gi (ctx-part of input gates), wih[:,0:5], bhh in registers.
// - split hi/lo MFMA (AhBh+AhBl+AlBh) == fp32-grade, same scheme as R7.
__global__ __launch_bounds__(512, 1) void gru4_kernel(
    const float* __restrict__ ctxf, const float* __restrict__ wih,
    const float* __restrict__ bih, const float* __restrict__ whh,
    const float* __restrict__ bhh,
    const float* __restrict__ mu_w1, const float* __restrict__ mu_b1,
    const float* __restrict__ mu_w2, const float* __restrict__ mu_b2,
    const float* __restrict__ vol_w1, const float* __restrict__ vol_b1,
    const float* __restrict__ vol_w2, const float* __restrict__ vol_b2,
    const float* __restrict__ rv, float* __restrict__ out)
{
    __shared__ alignas(16) bf16 hdh[2][16*136];
    __shared__ alignas(16) bf16 hdl[2][16*136];
    __shared__ float gi_s[16*388];
    __shared__ float g1_s[16*132];
    __shared__ float step_s[80];
    __shared__ float w2m_s[320], w2v_s[320];
    __shared__ float rvv[16];
    const int tid = threadIdx.x, lane = tid & 63, wave = tid >> 6;  // 8 waves
    const int q = lane >> 4, ml = lane & 15;
    const int col = wave*16 + ml;            // this lane's output column
    const int r0 = blockIdx.x * 16;

    // ---- recurrent weights: 3 gate tiles (cols col, 128+col, 256+col)
    bf16x8 wbh1[3][4], wbl1[3][4], wbh2[4], wbl2[4];
    float gi0[4], gi1[4], gi2[4];
    float w50[5], w51[5], w52[5];
    #pragma unroll
    for (int g = 0; g < 3; ++g) {
        int n = g*128 + col;
        #pragma unroll
        for (int s = 0; s < 4; ++s) {
            const float* wp = whh + (size_t)n*128 + s*32 + q*8;
            float4 f0 = *(const float4*)wp;
            float4 f1 = *(const float4*)(wp + 4);
            float v[8] = {f0.x,f0.y,f0.z,f0.w,f1.x,f1.y,f1.z,f1.w};
            bf16x8 hi, lo;
            #pragma unroll
            for (int j = 0; j < 8; ++j) {
                bf16 hb = (bf16)v[j]; hi[j] = hb; lo[j] = (bf16)(v[j] - (float)hb);
            }
            wbh1[g][s] = hi; wbl1[g][s] = lo;
        }
        #pragma unroll
        for (int j = 0; j < 5; ++j) {
            float wv = wih[(size_t)n*133 + j];
            if (g == 0) w50[j] = wv; else if (g == 1) w51[j] = wv; else w52[j] = wv;
        }
    }
    const float bhh0 = bhh[col], bhh1 = bhh[128 + col], bhh2 = bhh[256 + col];
    // ---- head weights: wave w owns head cols col (0..127): mu rows <64
    float bias2 = (col < 64) ? mu_b1[col] : vol_b1[col - 64];
    #pragma unroll
    for (int s = 0; s < 4; ++s) {
        const float* wp = ((col < 64) ? (mu_w1 + (size_t)col*128)
                                      : (vol_w1 + (size_t)(col-64)*128)) + s*32 + q*8;
        float4 f0 = *(const float4*)wp;
        float4 f1 = *(const float4*)(wp + 4);
        float v[8] = {f0.x,f0.y,f0.z,f0.w,f1.x,f1.y,f1.z,f1.w};
        bf16x8 hi, lo;
        #pragma unroll
        for (int j = 0; j < 8; ++j) {
            bf16 hb = (bf16)v[j]; hi[j] = hb; lo[j] = (bf16)(v[j] - (float)hb);
        }
        wbh2[s] = hi; wbl2[s] = lo;
    }

    // ---- init: stage ctx into g1_s (temp), hd hi/lo buf0, small arrays
    for (int i = tid; i < 2048; i += 512) {
        int rr = i >> 7, d = i & 127;
        float v = ctxf[(size_t)r0*128 + i];
        g1_s[rr*132 + d] = v;
        bf16 hb = (bf16)v;
        hdh[0][rr*136 + d] = hb;
        hdl[0][rr*136 + d] = (bf16)(v - (float)hb);
    }
    for (int i = tid; i < 320; i += 512) { w2m_s[i] = mu_w2[i]; w2v_s[i] = vol_w2[i]; }
    if (tid < 80) step_s[tid] = 0.f;
    if (tid < 16) rvv[tid] = 1.f + rv[r0 + tid];
    __syncthreads();
    // gi = bih + ctx @ wihc^T (one-time, fp32 exact)
    for (int idx = tid; idx < 6144; idx += 512) {
        int rr = idx / 384, n = idx % 384;
        const float* wr = wih + (size_t)n*133 + 5;
        float a = bih[n];
        #pragma unroll 4
        for (int k = 0; k < 128; ++k) a += g1_s[rr*132 + k] * wr[k];
        gi_s[rr*388 + n] = a;
    }
    __syncthreads();
    #pragma unroll
    for (int r = 0; r < 4; ++r) {
        int row = q*4 + r;
        gi0[r] = gi_s[row*388 + col];
        gi1[r] = gi_s[row*388 + 128 + col];
        gi2[r] = gi_s[row*388 + 256 + col];
    }
    __syncthreads();

    int cur = 0;
    for (int st = 0; st < HOR; ++st) {
        const int nxt = cur ^ 1;
        // ---- fused gates: A-frags (direct hi/lo loads), 3 gate tiles, VALU
        {
            bf16x8 ah[4], al[4];
            #pragma unroll
            for (int s = 0; s < 4; ++s) {
                ah[s] = *(const bf16x8*)&hdh[cur][ml*136 + s*32 + q*8];
                al[s] = *(const bf16x8*)&hdl[cur][ml*136 + s*32 + q*8];
            }
            floatx4 ar = (floatx4){0.f,0.f,0.f,0.f};
            floatx4 az = (floatx4){0.f,0.f,0.f,0.f};
            floatx4 an = (floatx4){0.f,0.f,0.f,0.f};
            #pragma unroll
            for (int s = 0; s < 4; ++s) {
                ar = __builtin_amdgcn_mfma_f32_16x16x32_bf16(ah[s], wbh1[0][s], ar, 0, 0, 0);
                ar = __builtin_amdgcn_mfma_f32_16x16x32_bf16(ah[s], wbl1[0][s], ar, 0, 0, 0);
                ar = __builtin_amdgcn_mfma_f32_16x16x32_bf16(al[s], wbh1[0][s], ar, 0, 0, 0);
                az = __builtin_amdgcn_mfma_f32_16x16x32_bf16(ah[s], wbh1[1][s], az, 0, 0, 0);
                az = __builtin_amdgcn_mfma_f32_16x16x32_bf16(ah[s], wbl1[1][s], az, 0, 0, 0);
                az = __builtin_amdgcn_mfma_f32_16x16x32_bf16(al[s], wbh1[1][s], az, 0, 0, 0);
                an = __builtin_amdgcn_mfma_f32_16x16x32_bf16(ah[s], wbh1[2][s], an, 0, 0, 0);
                an = __builtin_amdgcn_mfma_f32_16x16x32_bf16(ah[s], wbl1[2][s], an, 0, 0, 0);
                an = __builtin_amdgcn_mfma_f32_16x16x32_bf16(al[s], wbh1[2][s], an, 0, 0, 0);
            }
            #pragma unroll
            for (int r = 0; r < 4; ++r) {
                int row = q*4 + r;
                float ir = gi0[r], iz = gi1[r], in_ = gi2[r];
                #pragma unroll
                for (int j = 0; j < 5; ++j) {
                    float sv = step_s[row*5 + j];
                    ir  += sv * w50[j];
                    iz  += sv * w51[j];
                    in_ += sv * w52[j];
                }
                float rg = fast_sigmoid(ir + ar[r] + bhh0);
                float zg = fast_sigmoid(iz + az[r] + bhh1);
                float nn = fast_tanh(in_ + rg*(an[r] + bhh2));
                float hold = (float)hdh[cur][row*136 + col] + (float)hdl[cur][row*136 + col];
                float hnew = (1.f - zg)*nn + zg*hold;
                bf16 hb = (bf16)hnew;
                hdh[nxt][row*136 + col] = hb;
                hdl[nxt][row*136 + col] = (bf16)(hnew - (float)hb);
            }
        }
        __syncthreads();
        // ---- heads: 1 tile per wave + erf-GELU
        {
            bf16x8 ah[4], al[4];
            #pragma unroll
            for (int s = 0; s < 4; ++s) {
                ah[s] = *(const bf16x8*)&hdh[nxt][ml*136 + s*32 + q*8];
                al[s] = *(const bf16x8*)&hdl[nxt][ml*136 + s*32 + q*8];
            }
            floatx4 a4 = (floatx4){0.f,0.f,0.f,0.f};
            #pragma unroll
            for (int s = 0; s < 4; ++s) {
                a4 = __builtin_amdgcn_mfma_f32_16x16x32_bf16(ah[s], wbh2[s], a4, 0, 0, 0);
                a4 = __builtin_amdgcn_mfma_f32_16x16x32_bf16(ah[s], wbl2[s], a4, 0, 0, 0);
                a4 = __builtin_amdgcn_mfma_f32_16x16x32_bf16(al[s], wbh2[s], a4, 0, 0, 0);
            }
            #pragma unroll
            for (int r = 0; r < 4; ++r) {
                float u = a4[r] + bias2;
                g1_s[(q*4 + r)*132 + col] = 0.5f*u*(1.f + erff(u*0.70710678118654752f));
            }
        }
        __syncthreads();
        // ---- w2 heads + pred + step update (80 lanes)
        if (tid < 80) {
            int rr = tid / 5, o = tid % 5;
            float am = mu_b2[o], av = vol_b2[o];
            const float* g1r = &g1_s[rr*132];
            #pragma unroll 8
            for (int j = 0; j < 64; ++j) {
                am += g1r[j]      * w2m_s[o*64 + j];
                av += g1r[64 + j] * w2v_s[o*64 + j];
            }
            float mu = tanhf(am);
            float sp = (av > 20.f) ? av : log1pf(expf(av));
            float pr = mu * sp * rvv[rr];
            step_s[tid] = pr;
            out[((size_t)(r0 + rr)*HOR + st)*MM + o] = pr;
        }
        __syncthreads();
        cur = nxt;
    }
}

// ---------------------------------------------------------------------------
extern "C" void kernel_launch(void* const* d_in, const int* in_sizes, int n_in,
                              void* d_out, int out_size, void* d_ws, size_t ws_size,
                              hipStream_t stream)
{
    (void)in_sizes; (void)n_in; (void)out_size;
    const float* x        = (const float*)d_in[0];
    const int*   sym_id   = (const int*)d_in[1];
    const int*   regime_id= (const int*)d_in[2];
    const float* sym_emb  = (const float*)d_in[3];
    const float* reg_emb  = (const float*)d_in[4];
    const float* in_w     = (const float*)d_in[5];
    const float* in_b     = (const float*)d_in[6];
    const float* qkv_w    = (const float*)d_in[7];
    const float* qkv_b    = (const float*)d_in[8];
    const float* out_w    = (const float*)d_in[9];
    const float* out_bv   = (const float*)d_in[10];
    const float* ln1_w    = (const float*)d_in[11];
    const float* ln1_b    = (const float*)d_in[12];
    const float* ln2_w    = (const float*)d_in[13];
    const float* ln2_b    = (const float*)d_in[14];
    const float* f1_w     = (const float*)d_in[15];
    const float* f1_b     = (const float*)d_in[16];
    const float* f2_w     = (const float*)d_in[17];
    const float* f2_b     = (const float*)d_in[18];
    const float* pool_w   = (const float*)d_in[19];
    const float* pool_b   = (const float*)d_in[20];
    const float* ctx_w    = (const float*)d_in[21];
    const float* ctx_b    = (const float*)d_in[22];
    const float* gru_wih  = (const float*)d_in[23];
    const float* gru_whh  = (const float*)d_in[24];
    const float* gru_bih  = (const float*)d_in[25];
    const float* gru_bhh  = (const float*)d_in[26];
    const float* mu_w1    = (const float*)d_in[27];
    const float* mu_b1    = (const float*)d_in[28];
    const float* mu_w2    = (const float*)d_in[29];
    const float* mu_b2    = (const float*)d_in[30];
    const float* vol_w1   = (const float*)d_in[31];
    const float* vol_b1   = (const float*)d_in[32];
    const float* vol_w2   = (const float*)d_in[33];
    const float* vol_b2   = (const float*)d_in[34];
    float* outp = (float*)d_out;

    char* ws = (char*)d_ws;
    size_t off = 0;
    auto alloc = [&](size_t bytes) -> void* {
        void* p = ws + off;
        off = (off + bytes + 255) & ~(size_t)255;
        return p;
    };
    float* h    = (float*)alloc((size_t)NROWS*DD*4);        // 62.9 MB fp32 residual
    bf16*  y    = (bf16*) alloc((size_t)NROWS*DD*2);        // 31.5 MB bf16 LN/attn out
    bf16*  wbf  = (bf16*) alloc((size_t)393216*2);
    float* ctxf = (float*)alloc((size_t)BB*DD*4);
    float* rv   = (float*)alloc((size_t)BB*4);
    // `big` (qkv / ffn-mid bf16 scratch) takes remaining workspace; chunk rows.
    size_t avail = (ws_size > off) ? (ws_size - off) : 0;
    int nch;
    if      (avail >= (size_t)NROWS*512*2)     nch = 1;   // 125.8 MB
    else if (avail >= (size_t)NROWS/2*512*2)   nch = 2;
    else                                       nch = 4;   // 31.5 MB
    const int RC = NROWS / nch;
    const int BC = BB / nch;
    bf16* big = (bf16*)(ws + off);

    prep_weights<<<1536, 256, 0, stream>>>(qkv_w, out_w, f1_w, f2_w, wbf);
    inproj2<<<NROWS, 128, 0, stream>>>(x, sym_id, sym_emb, in_w, in_b, h);

    for (int l = 0; l < 2; ++l) {
        const bf16* wqkv = wbf + l*49152;
        const bf16* wout = wbf + 98304 + l*16384;
        const bf16* wf1  = wbf + 131072 + l*65536;
        const bf16* wf2  = wbf + 262144 + l*65536;
        ln2b<<<NROWS, 128, 0, stream>>>(h, ln1_w + l*128, ln1_b + l*128, y);
        for (int c = 0; c < nch; ++c) {
            const size_t ro = (size_t)c*RC;
            gemm_kernel<0><<<dim3(RC/128, 3), 256, 0, stream>>>(
                y + ro*DD, wqkv, qkv_b + l*384, nullptr, big, 384, 128);
            attn_b16<<<BC*4, 256, 0, stream>>>(big, y + ro*DD);
        }
        gemm_kernel<2><<<dim3(NROWS/128, 1), 256, 0, stream>>>(
            y, wout, out_bv + l*128, h, h, 128, 128);
        ln2b<<<NROWS, 128, 0, stream>>>(h, ln2_w + l*128, ln2_b + l*128, y);
        for (int c = 0; c < nch; ++c) {
            const size_t ro = (size_t)c*RC;
            gemm_kernel<1><<<dim3(RC/128, 4), 256, 0, stream>>>(
                y + ro*DD, wf1, f1_b + l*512, nullptr, big, 512, 128);
            gemm_kernel<2><<<dim3(RC/128, 1), 256, 0, stream>>>(
                big, wf2, f2_b + l*128, h + ro*DD, h + ro*DD, 128, 512);
        }
    }

    pool_ctx2<<<BB, 128, 0, stream>>>(h, x, sym_id, regime_id, sym_emb, reg_emb,
                                      pool_w, pool_b, ctx_w, ctx_b, ctxf, rv);
    gru4_kernel<<<64, 512, 0, stream>>>(ctxf, gru_wih, gru_bih, gru_whh, gru_bhh,
                                        mu_w1, mu_b1, mu_w2, mu_b2,
                                        vol_w1, vol_b1, vol_w2, vol_b2,
                                        rv, outp);
}

// Round 9
// 1703.008 us; speedup vs baseline: 2.7732x; 1.0285x over previous
//
#include <hip/hip_runtime.h>
#include <math.h>

typedef __bf16 bf16;
typedef __bf16 bf16x8 __attribute__((ext_vector_type(8)));
typedef __bf16 bf16x2 __attribute__((ext_vector_type(2)));
typedef float  floatx4 __attribute__((ext_vector_type(4)));

// dims
#define BB 1024
#define TT 120
#define FF 32
#define DD 128
#define NROWS (BB*TT)      // 122880
#define HOR 90
#define MM 5

__device__ __forceinline__ float fast_sigmoid(float x) {
    x = fminf(fmaxf(x, -30.f), 30.f);
    return 1.f / (1.f + __expf(-x));
}
__device__ __forceinline__ float fast_tanh(float x) {
    x = fminf(fmaxf(x, -15.f), 15.f);
    float e = __expf(-2.f * x);
    return (1.f - e) / (1.f + e);
}

// ---------------------------------------------------------------------------
// Encoder weights -> bf16.
__global__ __launch_bounds__(256) void prep_weights(
    const float* __restrict__ qkv, const float* __restrict__ outw,
    const float* __restrict__ f1,  const float* __restrict__ f2,
    bf16* __restrict__ dst)
{
    int i = blockIdx.x*256 + threadIdx.x;
    if (i >= 393216) return;
    float v;
    if      (i < 98304)  v = qkv[i];
    else if (i < 131072) v = outw[i - 98304];
    else if (i < 262144) v = f1[i - 131072];
    else                 v = f2[i - 262144];
    dst[i] = (bf16)v;
}

// ---------------------------------------------------------------------------
// Input projection + PE + fused ln1(L0). 4 rows/block, one wave per row.
// Writes h fp32 and y = LN(h) bf16.
__global__ __launch_bounds__(256) void inproj3(
    const float* __restrict__ x, const int* __restrict__ sym_id,
    const float* __restrict__ sym_emb, const float* __restrict__ in_w,
    const float* __restrict__ in_b, const float* __restrict__ lnw,
    const float* __restrict__ lnb, float* __restrict__ h, bf16* __restrict__ y)
{
    __shared__ float xin[4][48];
    const int tid = threadIdx.x, lane = tid & 63, wave = tid >> 6;
    const int row0 = blockIdx.x * 4;
    if (tid < 192) {                       // 4*48 = 192 <= 256 : fully staged
        int rr = tid / 48, k = tid % 48;
        int row = row0 + rr;
        int b = row / TT;
        xin[rr][k] = (k < 32) ? x[(size_t)row*FF + k]
                              : sym_emb[(size_t)sym_id[b]*16 + (k - 32)];
    }
    __syncthreads();
    const int row = row0 + wave;
    const int t = row % TT;
    const int d0 = lane*2;
    float a0 = in_b[d0], a1 = in_b[d0+1];
    const float* w0 = in_w + (size_t)d0*48;
    const float* w1 = w0 + 48;
    #pragma unroll 8
    for (int k = 0; k < 48; ++k) {
        float xv = xin[wave][k];
        a0 += xv * w0[k];
        a1 += xv * w1[k];
    }
    const float f = expf((float)d0 * (-9.210340371976184f / 128.f));
    const float arg = (float)t * f;
    a0 += sinf(arg);
    a1 += cosf(arg);
    float2 hv = {a0, a1};
    *(float2*)&h[(size_t)row*DD + d0] = hv;
    float s = a0 + a1, ss = a0*a0 + a1*a1;
    #pragma unroll
    for (int o = 1; o < 64; o <<= 1) { s += __shfl_xor(s, o); ss += __shfl_xor(ss, o); }
    float mean = s * (1.f/128.f);
    float var  = ss * (1.f/128.f) - mean*mean;
    float rstd = rsqrtf(var + 1e-5f);
    bf16x2 o2 = {(bf16)((a0 - mean)*rstd*lnw[d0]   + lnb[d0]),
                 (bf16)((a1 - mean)*rstd*lnw[d0+1] + lnb[d0+1])};
    *(bf16x2*)&y[(size_t)row*DD + d0] = o2;
}

// ---------------------------------------------------------------------------
// bf16 MFMA GEMM: out = A[M,K] @ W[N,K]^T + bias.
// EPI: 0 bias->bf16, 1 bias+relu->bf16, 2 bias+res->f32 h,
//      3 bias+res->f32 h AND row-LN->bf16 y (requires N==128).
template<int EPI>
__global__ __launch_bounds__(256) void gemm_kernel(
    const bf16* __restrict__ A, const bf16* __restrict__ W,
    const float* __restrict__ bias, const float* __restrict__ res,
    void* __restrict__ outp, const float* __restrict__ lnw,
    const float* __restrict__ lnb, bf16* __restrict__ yout, int N, int K)
{
    __shared__ alignas(16) bf16 As[128*128];
    __shared__ alignas(16) bf16 Ws[128*128];
    __shared__ float psum[2][128];
    __shared__ float psq[2][128];
    const int tid = threadIdx.x;
    const int lane = tid & 63, wave = tid >> 6;
    const int q = lane >> 4, ml = lane & 15;
    const int wm = (wave & 1) * 64, wn = (wave >> 1) * 64;
    const int m0 = blockIdx.x * 128, n0 = blockIdx.y * 128;
    floatx4 acc[4][4];
    #pragma unroll
    for (int i = 0; i < 4; ++i)
        #pragma unroll
        for (int j = 0; j < 4; ++j) acc[i][j] = (floatx4){0.f,0.f,0.f,0.f};
    const int nkb = K >> 7;
    for (int kb = 0; kb < nkb; ++kb) {
        #pragma unroll
        for (int i = 0; i < 8; ++i) {
            int idx = i*256 + tid;
            int r = idx >> 4, cc = idx & 15;
            uint4 va = *(const uint4*)(A + (size_t)(m0 + r)*K + kb*128 + cc*8);
            *(uint4*)&As[r*128 + ((cc ^ (r & 15))*8)] = va;
            uint4 vw = *(const uint4*)(W + (size_t)(n0 + r)*K + kb*128 + cc*8);
            *(uint4*)&Ws[r*128 + ((cc ^ (r & 15))*8)] = vw;
        }
        __syncthreads();
        #pragma unroll
        for (int s = 0; s < 4; ++s) {
            bf16x8 af[4], bfr[4];
            #pragma unroll
            for (int t = 0; t < 4; ++t) {
                int ra = wm + t*16 + ml;
                af[t]  = *(const bf16x8*)&As[ra*128 + (((4*s+q) ^ (ra & 15))*8)];
                int rb = wn + t*16 + ml;
                bfr[t] = *(const bf16x8*)&Ws[rb*128 + (((4*s+q) ^ (rb & 15))*8)];
            }
            #pragma unroll
            for (int i = 0; i < 4; ++i)
                #pragma unroll
                for (int j = 0; j < 4; ++j)
                    acc[i][j] = __builtin_amdgcn_mfma_f32_16x16x32_bf16(af[i], bfr[j], acc[i][j], 0, 0, 0);
        }
        __syncthreads();
    }
    #pragma unroll
    for (int j = 0; j < 4; ++j) {
        int col = n0 + wn + j*16 + ml;
        float bv = bias[col];
        #pragma unroll
        for (int i = 0; i < 4; ++i) {
            #pragma unroll
            for (int r = 0; r < 4; ++r) {
                int row = m0 + wm + i*16 + q*4 + r;
                size_t o = (size_t)row * N + col;
                float v = acc[i][j][r] + bv;
                if      (EPI == 0) ((bf16*)outp)[o] = (bf16)v;
                else if (EPI == 1) ((bf16*)outp)[o] = (bf16)fmaxf(v, 0.f);
                else {
                    v += res[o];
                    ((float*)outp)[o] = v;
                    acc[i][j][r] = v;          // keep for fused LN
                }
            }
        }
    }
    if (EPI == 3) {
        // fused row-LN (N==128): shuffle partials + cross-wave LDS combine
        float lw[4], lb[4];
        #pragma unroll
        for (int j = 0; j < 4; ++j) { int col = wn + j*16 + ml; lw[j] = lnw[col]; lb[j] = lnb[col]; }
        #pragma unroll
        for (int i = 0; i < 4; ++i)
            #pragma unroll
            for (int r = 0; r < 4; ++r) {
                float s  = acc[i][0][r] + acc[i][1][r] + acc[i][2][r] + acc[i][3][r];
                float ss = acc[i][0][r]*acc[i][0][r] + acc[i][1][r]*acc[i][1][r]
                         + acc[i][2][r]*acc[i][2][r] + acc[i][3][r]*acc[i][3][r];
                #pragma unroll
                for (int o = 1; o < 16; o <<= 1) { s += __shfl_xor(s, o); ss += __shfl_xor(ss, o); }
                if (ml == 0) {
                    int row = wm + i*16 + q*4 + r;
                    psum[wn >> 6][row] = s;
                    psq [wn >> 6][row] = ss;
                }
            }
        __syncthreads();
        #pragma unroll
        for (int i = 0; i < 4; ++i)
            #pragma unroll
            for (int r = 0; r < 4; ++r) {
                int row = wm + i*16 + q*4 + r;
                float mean = (psum[0][row] + psum[1][row]) * (1.f/128.f);
                float var  = (psq[0][row] + psq[1][row]) * (1.f/128.f) - mean*mean;
                float rstd = rsqrtf(var + 1e-5f);
                #pragma unroll
                for (int j = 0; j < 4; ++j) {
                    int col = wn + j*16 + ml;
                    yout[(size_t)(m0 + row)*128 + col] =
                        (bf16)((acc[i][j][r] - mean)*rstd*lw[j] + lb[j]);
                }
            }
    }
}

// ---------------------------------------------------------------------------
// bf16 MFMA attention (proven R8). One block per (b,h).
__global__ __launch_bounds__(256) void attn_b16(
    const bf16* __restrict__ qkv, bf16* __restrict__ O)
{
    __shared__ alignas(16) bf16 Qs[128*32];
    __shared__ alignas(16) bf16 Ks[128*32];
    __shared__ alignas(16) bf16 VT[32*128];
    __shared__ float Sf[64*132];
    const int tid = threadIdx.x, lane = tid & 63, wave = tid >> 6;
    const int q = lane >> 4, ml = lane & 15;
    const int b = blockIdx.x >> 2, hh = blockIdx.x & 3;
    const bf16* base = qkv + (size_t)b*TT*384 + hh*32;
    #pragma unroll
    for (int i = 0; i < 2; ++i) {
        int idx = i*256 + tid;
        int r = idx >> 2, cc = idx & 3;
        uint4 vq = {0,0,0,0}, vk = {0,0,0,0};
        if (r < TT) {
            vq = *(const uint4*)(base + (size_t)r*384 + cc*8);
            vk = *(const uint4*)(base + (size_t)r*384 + 128 + cc*8);
        }
        int cs = cc ^ ((r >> 1) & 3);
        *(uint4*)&Qs[r*32 + cs*8] = vq;
        *(uint4*)&Ks[r*32 + cs*8] = vk;
    }
    #pragma unroll
    for (int i = 0; i < 16; ++i) {
        int idx = i*256 + tid;
        int t = idx >> 5, e = idx & 31;
        bf16 v = (bf16)0.f;
        if (t < TT) v = base[(size_t)t*384 + 256 + e];
        VT[e*128 + (((t >> 3) ^ (e & 15))*8) + (t & 7)] = v;
    }
    __syncthreads();
    const float scale = 0.17677669529663687f;
    for (int hf = 0; hf < 2; ++hf) {
        {
            int rowa = hf*64 + wave*16 + ml;
            bf16x8 af = *(const bf16x8*)&Qs[rowa*32 + ((q ^ ((rowa>>1)&3))*8)];
            #pragma unroll
            for (int ni = 0; ni < 8; ++ni) {
                int rowb = ni*16 + ml;
                bf16x8 bfr = *(const bf16x8*)&Ks[rowb*32 + ((q ^ ((rowb>>1)&3))*8)];
                floatx4 a4 = __builtin_amdgcn_mfma_f32_16x16x32_bf16(
                    af, bfr, (floatx4){0.f,0.f,0.f,0.f}, 0, 0, 0);
                #pragma unroll
                for (int r = 0; r < 4; ++r)
                    Sf[(wave*16 + q*4 + r)*132 + ni*16 + ml] = a4[r]*scale;
            }
        }
        __syncthreads();
        for (int i = 0; i < 16; ++i) {
            int rl = wave*16 + i;
            int rg = hf*64 + rl;
            if (rg < TT) {
                float v0 = Sf[rl*132 + lane];
                bool ok1 = (lane + 64) < TT;
                float v1 = ok1 ? Sf[rl*132 + lane + 64] : -3e38f;
                float mx = fmaxf(v0, v1);
                #pragma unroll
                for (int o = 1; o < 64; o <<= 1) mx = fmaxf(mx, __shfl_xor(mx, o));
                float e0 = expf(v0 - mx);
                float e1 = ok1 ? expf(v1 - mx) : 0.f;
                float sm = e0 + e1;
                #pragma unroll
                for (int o = 1; o < 64; o <<= 1) sm += __shfl_xor(sm, o);
                float inv = 1.f / sm;
                Sf[rl*132 + lane]      = e0 * inv;
                Sf[rl*132 + lane + 64] = e1 * inv;
            }
        }
        __syncthreads();
        floatx4 pacc[2];
        pacc[0] = (floatx4){0.f,0.f,0.f,0.f};
        pacc[1] = (floatx4){0.f,0.f,0.f,0.f};
        #pragma unroll
        for (int s = 0; s < 4; ++s) {
            const float* pr = &Sf[(wave*16 + ml)*132 + 32*s + 8*q];
            float4 p0 = *(const float4*)pr;
            float4 p1 = *(const float4*)(pr + 4);
            bf16x8 af2 = {(bf16)p0.x,(bf16)p0.y,(bf16)p0.z,(bf16)p0.w,
                          (bf16)p1.x,(bf16)p1.y,(bf16)p1.z,(bf16)p1.w};
            #pragma unroll
            for (int nv = 0; nv < 2; ++nv) {
                int e = nv*16 + ml;
                bf16x8 bfr = *(const bf16x8*)&VT[e*128 + ((((4*s+q) ^ (e & 15)))*8)];
                pacc[nv] = __builtin_amdgcn_mfma_f32_16x16x32_bf16(af2, bfr, pacc[nv], 0, 0, 0);
            }
        }
        #pragma unroll
        for (int nv = 0; nv < 2; ++nv)
            #pragma unroll
            for (int r = 0; r < 4; ++r) {
                int row = hf*64 + wave*16 + q*4 + r;
                if (row < TT)
                    O[((size_t)b*TT + row)*DD + hh*32 + nv*16 + ml] = (bf16)pacc[nv][r];
            }
        __syncthreads();
    }
}

// ---------------------------------------------------------------------------
// Pool+ctx+rv: coalesced scores/pool (R2 structure, exonerated) + R5 ctx tail.
__global__ __launch_bounds__(128) void pool_ctx3(
    const float* __restrict__ h, const float* __restrict__ x,
    const int* __restrict__ sym_id, const int* __restrict__ regime_id,
    const float* __restrict__ sym_emb, const float* __restrict__ reg_emb,
    const float* __restrict__ pool_w, const float* __restrict__ pool_b,
    const float* __restrict__ ctx_w, const float* __restrict__ ctx_b,
    float* __restrict__ ctxf, float* __restrict__ rv)
{
    __shared__ float sc[120];
    __shared__ float aw[120];
    __shared__ float cat[152];
    const int b = blockIdx.x;
    const int tid = threadIdx.x, lane = tid & 63, wave = tid >> 6;  // 2 waves
    const float* hb = h + (size_t)b*TT*DD;
    for (int t = wave*60; t < wave*60 + 60; ++t) {
        const float2* hp = (const float2*)(hb + t*DD);
        float2 v = hp[lane];
        float s = v.x * pool_w[lane*2] + v.y * pool_w[lane*2 + 1];
        #pragma unroll
        for (int o = 1; o < 64; o <<= 1) s += __shfl_xor(s, o);
        if (lane == 0) sc[t] = s + pool_b[0];
    }
    __syncthreads();
    if (wave == 0) {                       // softmax over time
        float v0 = sc[lane];
        float v1 = (lane < 56) ? sc[lane + 64] : -3e38f;
        float mx = fmaxf(v0, v1);
        #pragma unroll
        for (int o = 1; o < 64; o <<= 1) mx = fmaxf(mx, __shfl_xor(mx, o));
        float e0 = expf(v0 - mx);
        float e1 = (lane < 56) ? expf(v1 - mx) : 0.f;
        float sm = e0 + e1;
        #pragma unroll
        for (int o = 1; o < 64; o <<= 1) sm += __shfl_xor(sm, o);
        float inv = 1.f / sm;
        aw[lane] = e0 * inv;
        if (lane < 56) aw[lane + 64] = e1 * inv;
    } else {                               // realized vol (ddof=1)
        float v0 = x[((size_t)b*TT + lane)*FF];
        float v1 = (lane < 56) ? x[((size_t)b*TT + lane + 64)*FF] : 0.f;
        float s = v0 + v1;
        #pragma unroll
        for (int o = 1; o < 64; o <<= 1) s += __shfl_xor(s, o);
        float mean = s / 120.f;
        float d0 = v0 - mean, d1 = (lane < 56) ? (v1 - mean) : 0.f;
        float ss = d0*d0 + d1*d1;
        #pragma unroll
        for (int o = 1; o < 64; o <<= 1) ss += __shfl_xor(ss, o);
        if (lane == 0) rv[b] = sqrtf(ss / 119.f);
    }
    __syncthreads();
    {
        float p = 0.f;
        for (int t = 0; t < TT; ++t) p += aw[t] * hb[(size_t)t*DD + tid];
        cat[tid] = p;
    }
    if (tid < 16)      cat[128 + tid] = sym_emb[(size_t)sym_id[b]*16 + tid];
    else if (tid < 24) cat[144 + (tid-16)] = reg_emb[regime_id[b]*8 + (tid-16)];
    __syncthreads();
    float acc = ctx_b[tid];
    const float* wr = ctx_w + (size_t)tid*152;
    for (int j = 0; j < 152; ++j) acc += cat[j] * wr[j];
    ctxf[(size_t)b*128 + tid] = acc;
}

// ---------------------------------------------------------------------------
// GRU v5: 64 blocks x 16 rows x 512 threads. Swizzled hd (conflict-free
// b128 frag loads), split MFMA chains, parallel w2 via shuffles.
#define G1IDX(rr,c) ((rr)*132 + (c) + ((c)>>5))
__global__ __launch_bounds__(512, 1) void gru5_kernel(
    const float* __restrict__ ctxf, const float* __restrict__ wih,
    const float* __restrict__ bih, const float* __restrict__ whh,
    const float* __restrict__ bhh,
    const float* __restrict__ mu_w1, const float* __restrict__ mu_b1,
    const float* __restrict__ mu_w2, const float* __restrict__ mu_b2,
    const float* __restrict__ vol_w1, const float* __restrict__ vol_b1,
    const float* __restrict__ vol_w2, const float* __restrict__ vol_b2,
    const float* __restrict__ rv, float* __restrict__ out)
{
    __shared__ alignas(16) bf16 hdh[2][16*128];
    __shared__ alignas(16) bf16 hdl[2][16*128];
    __shared__ float g1_s[16*132];
    __shared__ float step_s[80];
    __shared__ float w2m_s[320], w2v_s[320];
    __shared__ float rvv[16];
    const int tid = threadIdx.x, lane = tid & 63, wave = tid >> 6;  // 8 waves
    const int q = lane >> 4, ml = lane & 15;
    const int col = wave*16 + ml;
    const int r0 = blockIdx.x * 16;

    // ---- weights -> split hi/lo register fragments
    bf16x8 wbh1[3][4], wbl1[3][4], wbh2[4], wbl2[4];
    float w50[5], w51[5], w52[5];
    #pragma unroll
    for (int g = 0; g < 3; ++g) {
        int n = g*128 + col;
        #pragma unroll
        for (int s = 0; s < 4; ++s) {
            const float* wp = whh + (size_t)n*128 + s*32 + q*8;
            float4 f0 = *(const float4*)wp;
            float4 f1 = *(const float4*)(wp + 4);
            float v[8] = {f0.x,f0.y,f0.z,f0.w,f1.x,f1.y,f1.z,f1.w};
            bf16x8 hi, lo;
            #pragma unroll
            for (int j = 0; j < 8; ++j) {
                bf16 hb = (bf16)v[j]; hi[j] = hb; lo[j] = (bf16)(v[j] - (float)hb);
            }
            wbh1[g][s] = hi; wbl1[g][s] = lo;
        }
        #pragma unroll
        for (int j = 0; j < 5; ++j) {
            float wv = wih[(size_t)n*133 + j];
            if (g == 0) w50[j] = wv; else if (g == 1) w51[j] = wv; else w52[j] = wv;
        }
    }
    const float bhh0 = bhh[col], bhh1 = bhh[128 + col], bhh2 = bhh[256 + col];
    float bias2 = (col < 64) ? mu_b1[col] : vol_b1[col - 64];
    #pragma unroll
    for (int s = 0; s < 4; ++s) {
        const float* wp = ((col < 64) ? (mu_w1 + (size_t)col*128)
                                      : (vol_w1 + (size_t)(col-64)*128)) + s*32 + q*8;
        float4 f0 = *(const float4*)wp;
        float4 f1 = *(const float4*)(wp + 4);
        float v[8] = {f0.x,f0.y,f0.z,f0.w,f1.x,f1.y,f1.z,f1.w};
        bf16x8 hi, lo;
        #pragma unroll
        for (int j = 0; j < 8; ++j) {
            bf16 hb = (bf16)v[j]; hi[j] = hb; lo[j] = (bf16)(v[j] - (float)hb);
        }
        wbh2[s] = hi; wbl2[s] = lo;
    }

    // ---- init: ctx -> g1_s (temp) + swizzled hd buf0
    for (int i = tid; i < 2048; i += 512) {
        int rr = i >> 7, d = i & 127;
        float v = ctxf[(size_t)r0*128 + i];
        g1_s[G1IDX(rr, d)] = v;
        int pos = rr*128 + (((d>>3) ^ rr) & 15)*8 + (d & 7);
        bf16 hb = (bf16)v;
        hdh[0][pos] = hb;
        hdl[0][pos] = (bf16)(v - (float)hb);
    }
    for (int i = tid; i < 320; i += 512) { w2m_s[i] = mu_w2[i]; w2v_s[i] = vol_w2[i]; }
    if (tid < 80) step_s[tid] = 0.f;
    if (tid < 16) rvv[tid] = 1.f + rv[r0 + tid];
    __syncthreads();
    // gi = bih + ctx @ wihc^T for this lane's (4 rows x 3 gates)
    float gi0[4], gi1[4], gi2[4];
    #pragma unroll
    for (int g = 0; g < 3; ++g) {
        int n = g*128 + col;
        const float* wr = wih + (size_t)n*133 + 5;
        #pragma unroll
        for (int r = 0; r < 4; ++r) {
            int row = q*4 + r;
            float a = bih[n];
            #pragma unroll 4
            for (int k = 0; k < 128; ++k) a += g1_s[G1IDX(row, k)] * wr[k];
            if (g == 0) gi0[r] = a; else if (g == 1) gi1[r] = a; else gi2[r] = a;
        }
    }
    __syncthreads();

    int cur = 0;
    for (int st = 0; st < HOR; ++st) {
        const int nxt = cur ^ 1;
        // ---- phase 1: fused gates
        {
            bf16x8 ah[4], al[4];
            #pragma unroll
            for (int s = 0; s < 4; ++s) {
                int off = ml*128 + (((s*4 + q) ^ ml) & 15)*8;
                ah[s] = *(const bf16x8*)&hdh[cur][off];
                al[s] = *(const bf16x8*)&hdl[cur][off];
            }
            floatx4 a1 = (floatx4){0,0,0,0}, a2 = (floatx4){0,0,0,0}, a3 = (floatx4){0,0,0,0};
            floatx4 b1 = (floatx4){0,0,0,0}, b2 = (floatx4){0,0,0,0}, b3 = (floatx4){0,0,0,0};
            floatx4 c1 = (floatx4){0,0,0,0}, c2 = (floatx4){0,0,0,0}, c3 = (floatx4){0,0,0,0};
            #pragma unroll
            for (int s = 0; s < 4; ++s) {
                a1 = __builtin_amdgcn_mfma_f32_16x16x32_bf16(ah[s], wbh1[0][s], a1, 0, 0, 0);
                a2 = __builtin_amdgcn_mfma_f32_16x16x32_bf16(ah[s], wbl1[0][s], a2, 0, 0, 0);
                a3 = __builtin_amdgcn_mfma_f32_16x16x32_bf16(al[s], wbh1[0][s], a3, 0, 0, 0);
                b1 = __builtin_amdgcn_mfma_f32_16x16x32_bf16(ah[s], wbh1[1][s], b1, 0, 0, 0);
                b2 = __builtin_amdgcn_mfma_f32_16x16x32_bf16(ah[s], wbl1[1][s], b2, 0, 0, 0);
                b3 = __builtin_amdgcn_mfma_f32_16x16x32_bf16(al[s], wbh1[1][s], b3, 0, 0, 0);
                c1 = __builtin_amdgcn_mfma_f32_16x16x32_bf16(ah[s], wbh1[2][s], c1, 0, 0, 0);
                c2 = __builtin_amdgcn_mfma_f32_16x16x32_bf16(ah[s], wbl1[2][s], c2, 0, 0, 0);
                c3 = __builtin_amdgcn_mfma_f32_16x16x32_bf16(al[s], wbh1[2][s], c3, 0, 0, 0);
            }
            floatx4 ar = a1 + a2 + a3;
            floatx4 az = b1 + b2 + b3;
            floatx4 an = c1 + c2 + c3;
            #pragma unroll
            for (int r = 0; r < 4; ++r) {
                int row = q*4 + r;
                float ir = gi0[r], iz = gi1[r], in_ = gi2[r];
                #pragma unroll
                for (int j = 0; j < 5; ++j) {
                    float sv = step_s[row*5 + j];
                    ir  += sv * w50[j];
                    iz  += sv * w51[j];
                    in_ += sv * w52[j];
                }
                float rg = fast_sigmoid(ir + ar[r] + bhh0);
                float zg = fast_sigmoid(iz + az[r] + bhh1);
                float nn = fast_tanh(in_ + rg*(an[r] + bhh2));
                int pos = row*128 + (((col>>3) ^ row) & 15)*8 + (col & 7);
                float hold = (float)hdh[cur][pos] + (float)hdl[cur][pos];
                float hnew = (1.f - zg)*nn + zg*hold;
                bf16 hb = (bf16)hnew;
                hdh[nxt][pos] = hb;
                hdl[nxt][pos] = (bf16)(hnew - (float)hb);
            }
        }
        __syncthreads();
        // ---- phase 2: head pre-acts + erf-GELU
        {
            bf16x8 ah[4], al[4];
            #pragma unroll
            for (int s = 0; s < 4; ++s) {
                int off = ml*128 + (((s*4 + q) ^ ml) & 15)*8;
                ah[s] = *(const bf16x8*)&hdh[nxt][off];
                al[s] = *(const bf16x8*)&hdl[nxt][off];
            }
            floatx4 d1 = (floatx4){0,0,0,0}, d2 = (floatx4){0,0,0,0}, d3 = (floatx4){0,0,0,0};
            #pragma unroll
            for (int s = 0; s < 4; ++s) {
                d1 = __builtin_amdgcn_mfma_f32_16x16x32_bf16(ah[s], wbh2[s], d1, 0, 0, 0);
                d2 = __builtin_amdgcn_mfma_f32_16x16x32_bf16(ah[s], wbl2[s], d2, 0, 0, 0);
                d3 = __builtin_amdgcn_mfma_f32_16x16x32_bf16(al[s], wbh2[s], d3, 0, 0, 0);
            }
            floatx4 a4 = d1 + d2 + d3;
            #pragma unroll
            for (int r = 0; r < 4; ++r) {
                float u = a4[r] + bias2;
                g1_s[G1IDX(q*4 + r, col)] = 0.5f*u*(1.f + erff(u*0.70710678118654752f));
            }
        }
        __syncthreads();
        // ---- phase 3: w2 heads, 320 lanes (waves 0-4), shuffle combine
        if (tid < 320) {
            int g = tid >> 2;                 // (rr,o) group 0..79
            int sub = tid & 3;
            int head = sub >> 1, half = sub & 1;
            int rr = g / 5, o = g % 5;
            const float* w2 = head ? w2v_s : w2m_s;
            int wb = o*64 + half*32;
            int gb = head*64 + half*32;
            float s = 0.f;
            #pragma unroll 8
            for (int j = 0; j < 32; ++j)
                s += g1_s[G1IDX(rr, gb + j)] * w2[wb + j];
            s += __shfl_xor(s, 1);            // combine halves
            float resv;
            if (head == 0) resv = tanhf(s + mu_b2[o]);
            else {
                float av = s + vol_b2[o];
                float sp = (av > 20.f) ? av : log1pf(expf(av));
                resv = sp * rvv[rr];
            }
            float other = __shfl_xor(resv, 2);   // swap mu <-> sg
            if (sub == 0) {
                float pr = resv * other;
                step_s[g] = pr;
                out[((size_t)(r0 + rr)*HOR + st)*MM + o] = pr;
            }
        }
        __syncthreads();
        cur = nxt;
    }
}

// ---------------------------------------------------------------------------
extern "C" void kernel_launch(void* const* d_in, const int* in_sizes, int n_in,
                              void* d_out, int out_size, void* d_ws, size_t ws_size,
                              hipStream_t stream)
{
    (void)in_sizes; (void)n_in; (void)out_size;
    const float* x        = (const float*)d_in[0];
    const int*   sym_id   = (const int*)d_in[1];
    const int*   regime_id= (const int*)d_in[2];
    const float* sym_emb  = (const float*)d_in[3];
    const float* reg_emb  = (const float*)d_in[4];
    const float* in_w     = (const float*)d_in[5];
    const float* in_b     = (const float*)d_in[6];
    const float* qkv_w    = (const float*)d_in[7];
    const float* qkv_b    = (const float*)d_in[8];
    const float* out_w    = (const float*)d_in[9];
    const float* out_bv   = (const float*)d_in[10];
    const float* ln1_w    = (const float*)d_in[11];
    const float* ln1_b    = (const float*)d_in[12];
    const float* ln2_w    = (const float*)d_in[13];
    const float* ln2_b    = (const float*)d_in[14];
    const float* f1_w     = (const float*)d_in[15];
    const float* f1_b     = (const float*)d_in[16];
    const float* f2_w     = (const float*)d_in[17];
    const float* f2_b     = (const float*)d_in[18];
    const float* pool_w   = (const float*)d_in[19];
    const float* pool_b   = (const float*)d_in[20];
    const float* ctx_w    = (const float*)d_in[21];
    const float* ctx_b    = (const float*)d_in[22];
    const float* gru_wih  = (const float*)d_in[23];
    const float* gru_whh  = (const float*)d_in[24];
    const float* gru_bih  = (const float*)d_in[25];
    const float* gru_bhh  = (const float*)d_in[26];
    const float* mu_w1    = (const float*)d_in[27];
    const float* mu_b1    = (const float*)d_in[28];
    const float* mu_w2    = (const float*)d_in[29];
    const float* mu_b2    = (const float*)d_in[30];
    const float* vol_w1   = (const float*)d_in[31];
    const float* vol_b1   = (const float*)d_in[32];
    const float* vol_w2   = (const float*)d_in[33];
    const float* vol_b2   = (const float*)d_in[34];
    float* outp = (float*)d_out;

    char* ws = (char*)d_ws;
    size_t off = 0;
    auto alloc = [&](size_t bytes) -> void* {
        void* p = ws + off;
        off = (off + bytes + 255) & ~(size_t)255;
        return p;
    };
    float* h    = (float*)alloc((size_t)NROWS*DD*4);        // 62.9 MB fp32 residual
    bf16*  y    = (bf16*) alloc((size_t)NROWS*DD*2);        // 31.5 MB bf16 activations
    bf16*  wbf  = (bf16*) alloc((size_t)393216*2);
    float* ctxf = (float*)alloc((size_t)BB*DD*4);
    float* rv   = (float*)alloc((size_t)BB*4);
    size_t avail = (ws_size > off) ? (ws_size - off) : 0;
    int nch;
    if      (avail >= (size_t)NROWS*512*2)     nch = 1;
    else if (avail >= (size_t)NROWS/2*512*2)   nch = 2;
    else                                       nch = 4;
    const int RC = NROWS / nch;
    const int BC = BB / nch;
    bf16* big = (bf16*)(ws + off);

    prep_weights<<<1536, 256, 0, stream>>>(qkv_w, out_w, f1_w, f2_w, wbf);
    // inproj + PE + fused ln1(layer0)
    inproj3<<<NROWS/4, 256, 0, stream>>>(x, sym_id, sym_emb, in_w, in_b,
                                         ln1_w, ln1_b, h, y);

    for (int l = 0; l < 2; ++l) {
        const bf16* wqkv = wbf + l*49152;
        const bf16* wout = wbf + 98304 + l*16384;
        const bf16* wf1  = wbf + 131072 + l*65536;
        const bf16* wf2  = wbf + 262144 + l*65536;
        for (int c = 0; c < nch; ++c) {
            const size_t ro = (size_t)c*RC;
            gemm_kernel<0><<<dim3(RC/128, 3), 256, 0, stream>>>(
                y + ro*DD, wqkv, qkv_b + l*384, nullptr, big,
                nullptr, nullptr, nullptr, 384, 128);
            attn_b16<<<BC*4, 256, 0, stream>>>(big, y + ro*DD);
        }
        // out-proj + residual + fused ln2(l)
        gemm_kernel<3><<<dim3(NROWS/128, 1), 256, 0, stream>>>(
            y, wout, out_bv + l*128, h, h, ln2_w + l*128, ln2_b + l*128, y, 128, 128);
        for (int c = 0; c < nch; ++c) {
            const size_t ro = (size_t)c*RC;
            gemm_kernel<1><<<dim3(RC/128, 4), 256, 0, stream>>>(
                y + ro*DD, wf1, f1_b + l*512, nullptr, big,
                nullptr, nullptr, nullptr, 512, 128);
            if (l == 0)   // ffn2 + residual + fused ln1(layer1)
                gemm_kernel<3><<<dim3(RC/128, 1), 256, 0, stream>>>(
                    big, wf2, f2_b + l*128, h + ro*DD, h + ro*DD,
                    ln1_w + 128, ln1_b + 128, y + ro*DD, 128, 512);
            else          // last ffn2: residual only (pool reads h)
                gemm_kernel<2><<<dim3(RC/128, 1), 256, 0, stream>>>(
                    big, wf2, f2_b + l*128, h + ro*DD, h + ro*DD,
                    nullptr, nullptr, nullptr, 128, 512);
        }
    }

    pool_ctx3<<<BB, 128, 0, stream>>>(h, x, sym_id, regime_id, sym_emb, reg_emb,
                                      pool_w, pool_b, ctx_w, ctx_b, ctxf, rv);
    gru5_kernel<<<64, 512, 0, stream>>>(ctxf, gru_wih, gru_bih, gru_whh, gru_bhh,
                                        mu_w1, mu_b1, mu_w2, mu_b2,
                                        vol_w1, vol_b1, vol_w2, vol_b2,
                                        rv, outp);
}